// Round 3
// baseline (650.294 us; speedup 1.0000x reference)
//
#include <hip/hip_runtime.h>
#include <stdint.h>

// ArcticDecoderLayer on MI355X (gfx950).
// Precision plan: f16 MFMA everywhere except (a) o-proj GEMM in f16 hi/lo split
// (3 MFMAs) because its error feeds MoE top-k routing, (b) routing itself in
// fp32, (c) RoPE phases in fp64 (matches numpy's float64 promotion).
// R7: deep-pipelined GEMM cores. The 2-phase __syncthreads structure drains
// vmcnt(0) every K-step (measured: up-proj MfmaUtil 18%, 1.5K cyc/K-step vs
// 80 cyc of MFMA). New core: 4 LDS buffers, depth-3 prefetch, ONE raw
// s_barrier per K-step, counted s_waitcnt vmcnt(2L) (never 0 in main loop).
// Race-free: stage(t+3) overwrites buf[(t-1)&3] and is issued after barrier t,
// when all waves have consumed buf[t-1] into registers.
// + XOR k-seg swizzle (pre-swizzled glds source, phys_seg = seg ^ ((row>>1)&3))
//   -> conflict-free ds_read_b128 (was 8-way, 4.45M conflict cycles).
// + MoE A staged via per-lane-address global_load_lds (clamped gather rows).
// T=2048 H=1024 NH=16 NKV=4 HD=64 I=2048 E=8 TOPK=2

typedef _Float16 f16;
typedef _Float16 f16x8 __attribute__((ext_vector_type(8)));
typedef _Float16 f16x4 __attribute__((ext_vector_type(4)));
typedef float f32x4 __attribute__((ext_vector_type(4)));

#define DEV __device__ __forceinline__

DEV void glds16(const void* g, void* l) {
  __builtin_amdgcn_global_load_lds((const __attribute__((address_space(1))) void*)g,
                                   (__attribute__((address_space(3))) void*)l, 16, 0, 0);
}

// ---------------- conversions ----------------
__global__ void cvt_f16_kernel(const float* __restrict__ in, f16* __restrict__ outp) {
  const size_t i = ((size_t)blockIdx.x * 256 + threadIdx.x) * 4;
  float4 f = *(const float4*)(in + i);
  f16x4 o;
  o[0] = (f16)f.x; o[1] = (f16)f.y; o[2] = (f16)f.z; o[3] = (f16)f.w;
  *(f16x4*)(outp + i) = o;
}

__global__ void cvt_f16x2_kernel(const float* __restrict__ in,
                                 f16* __restrict__ oh, f16* __restrict__ ol) {
  const size_t i = ((size_t)blockIdx.x * 256 + threadIdx.x) * 4;
  float4 f = *(const float4*)(in + i);
  f16x4 h, l;
  h[0] = (f16)f.x; l[0] = (f16)(f.x - (float)h[0]);
  h[1] = (f16)f.y; l[1] = (f16)(f.y - (float)h[1]);
  h[2] = (f16)f.z; l[2] = (f16)(f.z - (float)h[2]);
  h[3] = (f16)f.w; l[3] = (f16)(f.w - (float)h[3]);
  *(f16x4*)(oh + i) = h;
  *(f16x4*)(ol + i) = l;
}

// ---------------- RMS norms (wave per row, 1024 cols) ----------------
__global__ void rmsnorm_kernel(const float* __restrict__ in, const float* __restrict__ w,
                               f16* __restrict__ outp) {
  const int t = blockIdx.x * 4 + (threadIdx.x >> 6);
  const int lane = threadIdx.x & 63;
  const float* x = in + (size_t)t * 1024;
  float v[16]; float ss = 0.f;
#pragma unroll
  for (int j = 0; j < 16; j++) { float a = x[lane + 64 * j]; v[j] = a; ss += a * a; }
#pragma unroll
  for (int m = 1; m < 64; m <<= 1) ss += __shfl_xor(ss, m);
  const float rs = rsqrtf(ss * (1.f / 1024.f) + 1e-5f);
#pragma unroll
  for (int j = 0; j < 16; j++)
    outp[(size_t)t * 1024 + lane + 64 * j] = (f16)(v[j] * rs * w[lane + 64 * j]);
}

__global__ void rmsnorm_dual_kernel(const float* __restrict__ in,
                                    const float* __restrict__ w1, const float* __restrict__ w2,
                                    f16* __restrict__ o1, f16* __restrict__ o2) {
  const int t = blockIdx.x * 4 + (threadIdx.x >> 6);
  const int lane = threadIdx.x & 63;
  const float* x = in + (size_t)t * 1024;
  float v[16]; float ss = 0.f;
#pragma unroll
  for (int j = 0; j < 16; j++) { float a = x[lane + 64 * j]; v[j] = a; ss += a * a; }
#pragma unroll
  for (int m = 1; m < 64; m <<= 1) ss += __shfl_xor(ss, m);
  const float rs = rsqrtf(ss * (1.f / 1024.f) + 1e-5f);
#pragma unroll
  for (int j = 0; j < 16; j++) {
    float nv = v[j] * rs;
    size_t idx = (size_t)t * 1024 + lane + 64 * j;
    o1[idx] = (f16)(nv * w1[lane + 64 * j]);
    o2[idx] = (f16)(nv * w2[lane + 64 * j]);
  }
}

// ---------------- main GEMM: C[M,N] = A[M,K] * B[N,K]^T, 128xBN x32 tiles ----
// Depth-3 pipeline, 4 LDS buffers, counted vmcnt, 1 barrier/K-step.
// EPI: 0 = fp32 store, 1 = fp32 store + addsrc, 2 = f16 store
template <int EPI, int BN, int SPLITK = 1>
__global__ __launch_bounds__(256) void gemm_f16_kernel(
    const f16* __restrict__ A, const f16* __restrict__ B,
    void* __restrict__ outp, const float* __restrict__ addsrc,
    int M, int N, int K) {
  constexpr int JT = BN / 32;  // col fragments per wave (wave covers BN/2 cols)
  constexpr int L = (BN == 128) ? 4 : 3;  // glds per thread per K-tile
  __shared__ __attribute__((aligned(16))) f16 As[4][128 * 32];
  __shared__ __attribute__((aligned(16))) f16 Bs[4][BN * 32];
  const int tid = threadIdx.x;
  const size_t row0 = (size_t)blockIdx.y * 128, col0 = (size_t)blockIdx.x * BN;
  const int ks = (SPLITK > 1) ? (int)blockIdx.z : 0;
  const int kspan = K / SPLITK, kb = ks * kspan;
  const int nt = kspan >> 5;
  const int c0 = tid, c1 = tid + 256;
  // pre-swizzled global k-segment: phys seg (tid&3) holds logical seg ^((row>>1)&3)
  const int sw0 = ((c0 & 3) ^ ((c0 >> 3) & 3)) * 8;
  const int sw1 = ((c1 & 3) ^ ((c1 >> 3) & 3)) * 8;
  const f16* a0 = A + (row0 + (c0 >> 2)) * K + sw0;
  const f16* a1 = A + (row0 + (c1 >> 2)) * K + sw1;
  const f16* b0 = B + (col0 + (c0 >> 2)) * K + sw0;
  const f16* b1 = B + (col0 + ((BN == 128) ? (c1 >> 2) : 0)) * K + ((BN == 128) ? sw1 : 0);

  const int wave = tid >> 6, lane = tid & 63, lr = lane >> 4, lc = lane & 15;
  const int wr = wave >> 1, wc = wave & 1;
  const int rsw = (lr ^ ((lc >> 1) & 3)) * 8;  // swizzled read k-offset

  f32x4 acc[4][JT];
#pragma unroll
  for (int i = 0; i < 4; i++)
#pragma unroll
    for (int j = 0; j < JT; j++) acc[i][j] = (f32x4){0.f, 0.f, 0.f, 0.f};

  auto stage = [&](int k0, int buf) {
    glds16(a0 + k0, As[buf] + c0 * 8);
    glds16(a1 + k0, As[buf] + c1 * 8);
    glds16(b0 + k0, Bs[buf] + c0 * 8);
    if constexpr (BN == 128) glds16(b1 + k0, Bs[buf] + c1 * 8);
  };

  stage(kb, 0); stage(kb + 32, 1); stage(kb + 64, 2);
  for (int t = 0; t < nt; ++t) {
    if (t <= nt - 3)      asm volatile("s_waitcnt vmcnt(%0)" :: "n"(2 * L) : "memory");
    else if (t == nt - 2) asm volatile("s_waitcnt vmcnt(%0)" :: "n"(L) : "memory");
    else                  asm volatile("s_waitcnt vmcnt(0)" ::: "memory");
    __builtin_amdgcn_s_barrier();
    asm volatile("" ::: "memory");
    if (t + 3 < nt) stage(kb + (t + 3) * 32, (t + 3) & 3);
    const f16* Ab = As[t & 3];
    const f16* Bb = Bs[t & 3];
    f16x8 af[4], bfr[JT];
#pragma unroll
    for (int i = 0; i < 4; i++)
      af[i] = *(const f16x8*)(Ab + (wr * 64 + i * 16 + lc) * 32 + rsw);
#pragma unroll
    for (int j = 0; j < JT; j++)
      bfr[j] = *(const f16x8*)(Bb + (wc * (BN / 2) + j * 16 + lc) * 32 + rsw);
#pragma unroll
    for (int i = 0; i < 4; i++)
#pragma unroll
      for (int j = 0; j < JT; j++)
        acc[i][j] = __builtin_amdgcn_mfma_f32_16x16x32_f16(af[i], bfr[j], acc[i][j], 0, 0, 0);
  }

#pragma unroll
  for (int i = 0; i < 4; i++)
#pragma unroll
    for (int j = 0; j < JT; j++) {
      const size_t rbase = row0 + wr * 64 + i * 16 + lr * 4;
      const size_t col = col0 + wc * (BN / 2) + j * 16 + lc;
#pragma unroll
      for (int r = 0; r < 4; r++) {
        size_t idx = (rbase + r) * N + col;
        if constexpr (SPLITK > 1) {
          ((float*)outp)[(size_t)ks * M * N + idx] = acc[i][j][r];
        } else if constexpr (EPI == 0) ((float*)outp)[idx] = acc[i][j][r];
        else if constexpr (EPI == 1) ((float*)outp)[idx] = acc[i][j][r] + addsrc[idx];
        else ((f16*)outp)[idx] = (f16)acc[i][j][r];
      }
    }
}

// ---------------- o-proj GEMM, f16 hi/lo split (3 MFMAs), 128x64 ------------
// Depth-2 pipeline (3 buffers, 72 KB LDS -> 2 blk/CU), counted vmcnt.
// SPLITK>1: fp32 partials at outp + ks*M*N (no addsrc; add3 combines).
template <int SPLITK>
__global__ __launch_bounds__(256) void gemm_f16x2_add_kernel(
    const f16* __restrict__ Ah, const f16* __restrict__ Al,
    const f16* __restrict__ Bh, const f16* __restrict__ Bl,
    float* __restrict__ outp, const float* __restrict__ addsrc,
    int M, int N, int K) {
  __shared__ __attribute__((aligned(16))) f16 Ash[3][128 * 32];
  __shared__ __attribute__((aligned(16))) f16 Asl[3][128 * 32];
  __shared__ __attribute__((aligned(16))) f16 Bsh[3][64 * 32];
  __shared__ __attribute__((aligned(16))) f16 Bsl[3][64 * 32];
  const int tid = threadIdx.x;
  const size_t row0 = (size_t)blockIdx.y * 128, col0 = (size_t)blockIdx.x * 64;
  const int ks = (SPLITK > 1) ? (int)blockIdx.z : 0;
  const int kspan = K / SPLITK, kb = ks * kspan;
  const int nt = kspan >> 5;
  const int c0 = tid, c1 = tid + 256;
  const int sw0 = ((c0 & 3) ^ ((c0 >> 3) & 3)) * 8;
  const int sw1 = ((c1 & 3) ^ ((c1 >> 3) & 3)) * 8;
  const size_t aoff0 = (row0 + (c0 >> 2)) * K + sw0;
  const size_t aoff1 = (row0 + (c1 >> 2)) * K + sw1;
  const size_t boff0 = (col0 + (c0 >> 2)) * K + sw0;

  const int wave = tid >> 6, lane = tid & 63, lr = lane >> 4, lc = lane & 15;
  const int wr = wave >> 1, wc = wave & 1;
  const int rsw = (lr ^ ((lc >> 1) & 3)) * 8;

  f32x4 acc[4][2];
#pragma unroll
  for (int i = 0; i < 4; i++)
#pragma unroll
    for (int j = 0; j < 2; j++) acc[i][j] = (f32x4){0.f, 0.f, 0.f, 0.f};

  auto stage = [&](int k0, int buf) {
    glds16(Ah + aoff0 + k0, Ash[buf] + c0 * 8);
    glds16(Ah + aoff1 + k0, Ash[buf] + c1 * 8);
    glds16(Al + aoff0 + k0, Asl[buf] + c0 * 8);
    glds16(Al + aoff1 + k0, Asl[buf] + c1 * 8);
    glds16(Bh + boff0 + k0, Bsh[buf] + c0 * 8);
    glds16(Bl + boff0 + k0, Bsl[buf] + c0 * 8);
  };

  stage(kb, 0); stage(kb + 32, 1);
  int bc = 0, bs = 2;
  for (int t = 0; t < nt; ++t) {
    if (t <= nt - 2) asm volatile("s_waitcnt vmcnt(%0)" :: "n"(6) : "memory");
    else             asm volatile("s_waitcnt vmcnt(0)" ::: "memory");
    __builtin_amdgcn_s_barrier();
    asm volatile("" ::: "memory");
    if (t + 2 < nt) stage(kb + (t + 2) * 32, bs);
    f16x8 afh[4], afl[4], bfh[2], bfl[2];
#pragma unroll
    for (int i = 0; i < 4; i++) {
      const int ro = (wr * 64 + i * 16 + lc) * 32 + rsw;
      afh[i] = *(const f16x8*)(Ash[bc] + ro);
      afl[i] = *(const f16x8*)(Asl[bc] + ro);
    }
#pragma unroll
    for (int j = 0; j < 2; j++) {
      const int ro = (wc * 32 + j * 16 + lc) * 32 + rsw;
      bfh[j] = *(const f16x8*)(Bsh[bc] + ro);
      bfl[j] = *(const f16x8*)(Bsl[bc] + ro);
    }
#pragma unroll
    for (int i = 0; i < 4; i++)
#pragma unroll
      for (int j = 0; j < 2; j++) {
        acc[i][j] = __builtin_amdgcn_mfma_f32_16x16x32_f16(afh[i], bfh[j], acc[i][j], 0, 0, 0);
        acc[i][j] = __builtin_amdgcn_mfma_f32_16x16x32_f16(afh[i], bfl[j], acc[i][j], 0, 0, 0);
        acc[i][j] = __builtin_amdgcn_mfma_f32_16x16x32_f16(afl[i], bfh[j], acc[i][j], 0, 0, 0);
      }
    bc = (bc == 2) ? 0 : bc + 1;
    bs = (bs == 2) ? 0 : bs + 1;
  }

#pragma unroll
  for (int i = 0; i < 4; i++)
#pragma unroll
    for (int j = 0; j < 2; j++) {
      const size_t rbase = row0 + wr * 64 + i * 16 + lr * 4;
      const size_t col = col0 + wc * 32 + j * 16 + lc;
#pragma unroll
      for (int r = 0; r < 4; r++) {
        size_t idx = (rbase + r) * N + col;
        if constexpr (SPLITK > 1) outp[(size_t)ks * M * N + idx] = acc[i][j][r];
        else outp[idx] = acc[i][j][r] + addsrc[idx];
      }
    }
}

// ---------------- MoE GEMM: gathered A rows via perm, per-expert B -----------
// DIVROW=1: A row = sid>>1 (token) ; DIVROW=0: A row = sid (slot)
// A staged via per-lane-address glds (gather rows clamped to 0; garbage rows
// are row-local in MFMA and never stored). Depth-3 pipeline as dense.
// SPLITK>1: blockIdx.z = e*SPLITK + ks; fp32 partials at outp + ks*4096*N.
template <int DIVROW, int BN, int SPLITK = 1>
__global__ __launch_bounds__(256) void gemm_moe_kernel(
    const f16* __restrict__ A, const f16* __restrict__ Ball, void* __restrict__ outp,
    const int* __restrict__ perm, const int* __restrict__ counts,
    int N, int K, size_t strideB) {
  constexpr int JT = BN / 32;
  constexpr int L = (BN == 128) ? 4 : 3;
  const int e = (int)blockIdx.z / SPLITK;
  const int ks = (int)blockIdx.z % SPLITK;
  const int cnt = counts[e];
  const int bm = blockIdx.y;
  if (bm * 128 >= cnt) return;
  const int kspan = K / SPLITK, kb = ks * kspan;
  const int nt = kspan >> 5;
  const f16* B = Ball + (size_t)e * strideB;
  __shared__ __attribute__((aligned(16))) f16 As[4][128 * 32];
  __shared__ __attribute__((aligned(16))) f16 Bs[4][BN * 32];
  const int tid = threadIdx.x;
  const size_t col0 = (size_t)blockIdx.x * BN;
  const int c0 = tid, c1 = tid + 256;
  const int pbase = e * 2048 + bm * 128;
  const int rt0 = c0 >> 2, rt1 = c1 >> 2;
  const int sid0 = (bm * 128 + rt0 < cnt) ? perm[pbase + rt0] : 0;
  const int sid1 = (bm * 128 + rt1 < cnt) ? perm[pbase + rt1] : 0;
  const size_t ar0 = DIVROW ? (size_t)(sid0 >> 1) : (size_t)sid0;
  const size_t ar1 = DIVROW ? (size_t)(sid1 >> 1) : (size_t)sid1;
  const int sw0 = ((c0 & 3) ^ ((c0 >> 3) & 3)) * 8;
  const int sw1 = ((c1 & 3) ^ ((c1 >> 3) & 3)) * 8;
  const f16* ap0 = A + ar0 * K + sw0;
  const f16* ap1 = A + ar1 * K + sw1;
  const f16* b0 = B + (col0 + (c0 >> 2)) * K + sw0;
  const f16* b1 = B + (col0 + ((BN == 128) ? (c1 >> 2) : 0)) * K + ((BN == 128) ? sw1 : 0);

  const int wave = tid >> 6, lane = tid & 63, lr = lane >> 4, lc = lane & 15;
  const int wr = wave >> 1, wc = wave & 1;
  const int rsw = (lr ^ ((lc >> 1) & 3)) * 8;

  f32x4 acc[4][JT];
#pragma unroll
  for (int i = 0; i < 4; i++)
#pragma unroll
    for (int j = 0; j < JT; j++) acc[i][j] = (f32x4){0.f, 0.f, 0.f, 0.f};

  auto stage = [&](int k0, int buf) {
    glds16(ap0 + k0, As[buf] + c0 * 8);
    glds16(ap1 + k0, As[buf] + c1 * 8);
    glds16(b0 + k0, Bs[buf] + c0 * 8);
    if constexpr (BN == 128) glds16(b1 + k0, Bs[buf] + c1 * 8);
  };

  stage(kb, 0); stage(kb + 32, 1); stage(kb + 64, 2);
  for (int t = 0; t < nt; ++t) {
    if (t <= nt - 3)      asm volatile("s_waitcnt vmcnt(%0)" :: "n"(2 * L) : "memory");
    else if (t == nt - 2) asm volatile("s_waitcnt vmcnt(%0)" :: "n"(L) : "memory");
    else                  asm volatile("s_waitcnt vmcnt(0)" ::: "memory");
    __builtin_amdgcn_s_barrier();
    asm volatile("" ::: "memory");
    if (t + 3 < nt) stage(kb + (t + 3) * 32, (t + 3) & 3);
    const f16* Ab = As[t & 3];
    const f16* Bb = Bs[t & 3];
    f16x8 af[4], bfr[JT];
#pragma unroll
    for (int i = 0; i < 4; i++)
      af[i] = *(const f16x8*)(Ab + (wr * 64 + i * 16 + lc) * 32 + rsw);
#pragma unroll
    for (int j = 0; j < JT; j++)
      bfr[j] = *(const f16x8*)(Bb + (wc * (BN / 2) + j * 16 + lc) * 32 + rsw);
#pragma unroll
    for (int i = 0; i < 4; i++)
#pragma unroll
      for (int j = 0; j < JT; j++)
        acc[i][j] = __builtin_amdgcn_mfma_f32_16x16x32_f16(af[i], bfr[j], acc[i][j], 0, 0, 0);
  }

  int sids[4][4];
#pragma unroll
  for (int i = 0; i < 4; i++)
#pragma unroll
    for (int r = 0; r < 4; r++) {
      int rit = wr * 64 + i * 16 + lr * 4 + r;
      sids[i][r] = (bm * 128 + rit < cnt) ? perm[pbase + rit] : -1;
    }
#pragma unroll
  for (int i = 0; i < 4; i++)
#pragma unroll
    for (int j = 0; j < JT; j++) {
      const size_t col = col0 + wc * (BN / 2) + j * 16 + lc;
#pragma unroll
      for (int r = 0; r < 4; r++)
        if (sids[i][r] >= 0) {
          if constexpr (SPLITK > 1)
            ((float*)outp)[((size_t)ks * 4096 + sids[i][r]) * N + col] = acc[i][j][r];
          else
            ((f16*)outp)[(size_t)sids[i][r] * N + col] = (f16)acc[i][j][r];
        }
    }
}

// ---------------- RoPE (fp64 phases), reads qkv split partials (sum) --------
__global__ void rope_kernel(const float* __restrict__ qkv, const int* __restrict__ pos,
                            f16* __restrict__ qr, f16* __restrict__ kr) {
  const int t = blockIdx.y;
  const int u = blockIdx.x * 256 + threadIdx.x;  // 0..767, use 0..639
  if (u >= 640) return;
  const float* b0 = qkv + (size_t)t * 1536;
  const float* b1 = b0 + (size_t)2048 * 1536;
  const int head = u >> 5, i = u & 31;
  const bool isq = head < 16;
  const int off = isq ? head * 64 + i : 1024 + (head - 16) * 64 + i;
  const float x1 = b0[off] + b1[off], x2 = b0[off + 32] + b1[off + 32];
  const double ph = (double)pos[t] * exp((double)i * -0.28782313662425575);  // ln(1e4)/32
  const float c = (float)cos(ph), s = (float)sin(ph);
  const float r1 = x1 * c - x2 * s, r2 = x2 * c + x1 * s;
  if (isq) {
    // 0.125 * log2(e): base-2 softmax in attn
    const float qs = 0.18033688011116042f;
    qr[(size_t)t * 1024 + head * 64 + i] = (f16)(qs * r1);
    qr[(size_t)t * 1024 + head * 64 + i + 32] = (f16)(qs * r2);
  } else {
    const int kh = head - 16;
    kr[(size_t)t * 256 + kh * 64 + i] = (f16)r1;
    kr[(size_t)t * 256 + kh * 64 + i + 32] = (f16)r2;
  }
}

// ---------------- V transpose from qkv split partials (sum) -----------------
__global__ void vtrans_kernel(const float* __restrict__ qkvf, f16* __restrict__ vt) {
  __shared__ float Ts[64 * 69];
  const int t0 = blockIdx.x * 64;
  const int kv = blockIdx.y;
  const int tid = threadIdx.x;
  const int tr = tid >> 2, jj = tid & 3;
  const float* src0 = qkvf + (size_t)(t0 + tr) * 1536 + 1280 + kv * 64 + jj * 16;
  const float* src1 = src0 + (size_t)2048 * 1536;
#pragma unroll
  for (int x = 0; x < 4; x++) {
    float4 f = *(const float4*)(src0 + x * 4);
    float4 g = *(const float4*)(src1 + x * 4);
    Ts[tr * 69 + jj * 16 + x * 4 + 0] = f.x + g.x;
    Ts[tr * 69 + jj * 16 + x * 4 + 1] = f.y + g.y;
    Ts[tr * 69 + jj * 16 + x * 4 + 2] = f.z + g.z;
    Ts[tr * 69 + jj * 16 + x * 4 + 3] = f.w + g.w;
  }
  __syncthreads();
  f16* dst = vt + (size_t)(kv * 64 + tr) * 2048 + t0 + jj * 16;
#pragma unroll
  for (int x = 0; x < 2; x++) {
    f16x8 o;
#pragma unroll
    for (int i = 0; i < 8; i++) o[i] = (f16)Ts[(jj * 16 + x * 8 + i) * 69 + tr];
    *(f16x8*)(dst + x * 8) = o;
  }
}

// ---------------- add3: o = a + p0 + p1 (fp32, deterministic combine) -------
__global__ void add3_kernel(float* __restrict__ o, const float* __restrict__ a,
                            const float* __restrict__ p0, const float* __restrict__ p1) {
  const size_t i4 = ((size_t)blockIdx.x * 256 + threadIdx.x) * 4;
  float4 va = *(const float4*)(a + i4);
  float4 v0 = *(const float4*)(p0 + i4);
  float4 v1 = *(const float4*)(p1 + i4);
  va.x += v0.x + v1.x;
  va.y += v0.y + v1.y;
  va.z += v0.z + v1.z;
  va.w += v0.w + v1.w;
  *(float4*)(o + i4) = va;
}

// ---------------- flash attention v4: S^T = K*Q^T + LDS-staged K/V ----------
// 4 waves/block, each wave 16 q-rows (block = 64). K,V^T staged per 128-chunk
// into padded LDS (stride 72 / 136 f16 -> conflict-free b128 access). Next-chunk
// global loads prefetched into VGPRs during compute. 52 KB LDS -> 3 blk/CU.
__global__ __launch_bounds__(256, 3) void attn_kernel(
    const f16* __restrict__ qr, const f16* __restrict__ kr, const f16* __restrict__ vt,
    f16* __restrict__ ahi, f16* __restrict__ alo) {
  const int qt = 31 - (int)blockIdx.x;  // 64-row q tiles, heavy first
  const int h = blockIdx.y;
  const int kvh = h >> 2;
  __shared__ __attribute__((aligned(16))) f16 Ks[128 * 72];   // [k=128][d=64 +8pad]
  __shared__ __attribute__((aligned(16))) f16 Vs[64 * 136];   // [d=64][k=128 +8pad]
  __shared__ __attribute__((aligned(16))) f16 Pl[4 * 16 * 136];  // per-wave P^T strips
  const int tid = threadIdx.x;
  const int wave = tid >> 6, lane = tid & 63, lr = lane >> 4, lc = lane & 15;
  const int trow = qt * 64 + wave * 16 + lc;  // this lane's q row (S^T column)
  f16* Pw = Pl + wave * 16 * 136;

  // staging roles (whole block)
  const int krow = tid >> 3, kcol = (tid & 7) * 8;    // 32 k-rows per iter, 4 iters
  const int vrow = tid >> 4, vcol = (tid & 15) * 8;   // 16 d-rows per iter, 4 iters
  const f16* kgbase = kr + (size_t)kvh * 64 + kcol;
  const f16* vgbase = vt + (size_t)(kvh * 64 + vrow) * 2048 + vcol;

  // Q as B-operand: B[n=lc=t][k=d]
  const f16* qp = qr + (size_t)trow * 1024 + h * 64 + lr * 8;
  f16x8 qf0 = *(const f16x8*)(qp);
  f16x8 qf1 = *(const f16x8*)(qp + 32);

  float m_run = -3e38f, l_run = 0.f;
  f32x4 accO[4];
#pragma unroll
  for (int jo = 0; jo < 4; jo++) accO[jo] = (f32x4){0.f, 0.f, 0.f, 0.f};

  const int nch = (qt >> 1) + 1;  // 128-wide chunks

  f16x8 kreg[4], vreg[4];
  // preload chunk 0
#pragma unroll
  for (int it = 0; it < 4; it++) {
    kreg[it] = *(const f16x8*)(kgbase + (size_t)(it * 32 + krow) * 256);
    vreg[it] = *(const f16x8*)(vgbase + it * 16 * 2048);
  }

  for (int ch = 0; ch < nch; ++ch) {
    const int c0 = ch * 128;
    const bool last = (ch == nch - 1);

    __syncthreads();  // previous chunk's LDS reads complete
#pragma unroll
    for (int it = 0; it < 4; it++) {
      *(f16x8*)(Ks + (it * 32 + krow) * 72 + kcol) = kreg[it];
      *(f16x8*)(Vs + (it * 16 + vrow) * 136 + vcol) = vreg[it];
    }
    __syncthreads();  // staging visible

    // prefetch next chunk into regs (overlaps with compute below)
    if (!last) {
      const int c1 = c0 + 128;
#pragma unroll
      for (int it = 0; it < 4; it++) {
        kreg[it] = *(const f16x8*)(kgbase + (size_t)(c1 + it * 32 + krow) * 256);
        vreg[it] = *(const f16x8*)(vgbase + it * 16 * 2048 + c1);
      }
    }

    // ---- S^T tiles: A = K rows from LDS, B = Q frag ----
    f32x4 st[8];
#pragma unroll
    for (int j = 0; j < 8; j++) {
      const f16* kp = Ks + (j * 16 + lc) * 72 + lr * 8;
      f16x8 ka0 = *(const f16x8*)(kp);
      f16x8 ka1 = *(const f16x8*)(kp + 32);
      f32x4 s = (f32x4){0.f, 0.f, 0.f, 0.f};
      s = __builtin_amdgcn_mfma_f32_16x16x32_f16(ka0, qf0, s, 0, 0, 0);
      s = __builtin_amdgcn_mfma_f32_16x16x32_f16(ka1, qf1, s, 0, 0, 0);
      st[j] = s;
    }

    // ---- causal mask (only last chunk crosses the diagonal) ----
    if (last) {
#pragma unroll
      for (int j = 0; j < 8; j++)
#pragma unroll
        for (int r = 0; r < 4; r++)
          if (c0 + j * 16 + lr * 4 + r > trow) st[j][r] = -3e38f;
    }

    // ---- chunk max: in-lane over 32 regs + 2 shuffles ----
    float mc = -3e38f;
#pragma unroll
    for (int j = 0; j < 8; j++)
      mc = fmaxf(mc, fmaxf(fmaxf(st[j][0], st[j][1]), fmaxf(st[j][2], st[j][3])));
    mc = fmaxf(mc, __shfl_xor(mc, 16));
    mc = fmaxf(mc, __shfl_xor(mc, 32));
    const float mn = fmaxf(m_run, mc);
    const float alpha = __builtin_amdgcn_exp2f(m_run - mn);
    m_run = mn;

    // ---- exp2, packed P^T stores (b64, 2-way = free), in-lane sum ----
    float ls = 0.f;
#pragma unroll
    for (int j = 0; j < 8; j++) {
      f16x4 pv;
#pragma unroll
      for (int r = 0; r < 4; r++) {
        float e = __builtin_amdgcn_exp2f(st[j][r] - mn);
        ls += e;
        pv[r] = (f16)e;
      }
      *(f16x4*)(Pw + lc * 136 + j * 16 + lr * 4) = pv;  // P^T[t=lc][s]
    }
    ls += __shfl_xor(ls, 16);
    ls += __shfl_xor(ls, 32);
    l_run = l_run * alpha + ls;
#pragma unroll
    for (int jo = 0; jo < 4; jo++) accO[jo] *= alpha;

    // ---- O^T += V^T * P^T : A = V^T frags (LDS), B = P^T (wave-private) ----
#pragma unroll
    for (int kkt = 0; kkt < 4; kkt++) {
      f16x8 pb = *(const f16x8*)(Pw + lc * 136 + kkt * 32 + lr * 8);
#pragma unroll
      for (int jo = 0; jo < 4; jo++) {
        f16x8 va = *(const f16x8*)(Vs + (jo * 16 + lc) * 136 + kkt * 32 + lr * 8);
        accO[jo] = __builtin_amdgcn_mfma_f32_16x16x32_f16(va, pb, accO[jo], 0, 0, 0);
      }
    }
  }

  // ---- epilogue: O^T lane holds col t, rows d = jo*16+lr*4+r ----
  const float inv = 1.f / l_run;
#pragma unroll
  for (int jo = 0; jo < 4; jo++) {
    f16x4 hi4, lo4;
#pragma unroll
    for (int r = 0; r < 4; r++) {
      float o = accO[jo][r] * inv;
      f16 hv = (f16)o;
      hi4[r] = hv;
      lo4[r] = (f16)(o - (float)hv);
    }
    const size_t idx = (size_t)trow * 1024 + h * 64 + jo * 16 + lr * 4;
    *(f16x4*)(ahi + idx) = hi4;
    *(f16x4*)(alo + idx) = lo4;
  }
}

// ---------------- routing: fp32 norm + gate + top2, compaction --------------
__global__ void routing_kernel(const float* __restrict__ resA,
                               const float* __restrict__ postw,
                               const float* __restrict__ gw,
                               int* __restrict__ counts, int* __restrict__ perm,
                               float* __restrict__ rw) {
  const int t = blockIdx.x * 4 + (threadIdx.x >> 6);
  const int lane = threadIdx.x & 63;
  const float* x = resA + (size_t)t * 1024;
  float v[16]; float ss = 0.f;
#pragma unroll
  for (int j = 0; j < 16; j++) { float a = x[lane + 64 * j]; v[j] = a; ss += a * a; }
#pragma unroll
  for (int m = 1; m < 64; m <<= 1) ss += __shfl_xor(ss, m);
  const float rs = rsqrtf(ss * (1.f / 1024.f) + 1e-5f);
#pragma unroll
  for (int j = 0; j < 16; j++) v[j] *= rs * postw[lane + 64 * j];
  float lg[8];
#pragma unroll
  for (int e = 0; e < 8; e++) {
    float p = 0.f;
    const float* g = gw + (size_t)e * 1024;
#pragma unroll
    for (int j = 0; j < 16; j++) p += v[j] * g[lane + 64 * j];
#pragma unroll
    for (int m = 1; m < 64; m <<= 1) p += __shfl_xor(p, m);
    lg[e] = p;
  }
  if (lane == 0) {
    int e0 = 0; float b0 = lg[0];
#pragma unroll
    for (int e = 1; e < 8; e++) if (lg[e] > b0) { b0 = lg[e]; e0 = e; }
    int e1 = -1; float b1 = -3e38f;
#pragma unroll
    for (int e = 0; e < 8; e++) if (e != e0 && lg[e] > b1) { b1 = lg[e]; e1 = e; }
    const float w0 = 1.f / (1.f + expf(b1 - b0));  // p0/(p0+p1)
    const float w1 = 1.f - w0;
    int p0 = atomicAdd(&counts[e0], 1);
    perm[e0 * 2048 + p0] = t * 2;
    int p1 = atomicAdd(&counts[e1], 1);
    perm[e1 * 2048 + p1] = t * 2 + 1;
    rw[t * 2] = w0;
    rw[t * 2 + 1] = w1;
  }
}

// ---------------- silu(g)*u ----------------
__global__ void silu_mul_kernel(const f16* __restrict__ gu, f16* __restrict__ outp, int lgN) {
  const int N = 1 << lgN;
  const size_t i4 = ((size_t)blockIdx.x * 256 + threadIdx.x) * 4;
  const size_t r = i4 >> lgN;
  const int c = (int)(i4 & (N - 1));
  const f16* gp = gu + r * (size_t)(2 * N) + c;
  f16x4 g = *(const f16x4*)gp;
  f16x4 u = *(const f16x4*)(gp + N);
  f16x4 o;
#pragma unroll
  for (int x = 0; x < 4; x++) {
    float gg = (float)g[x], uu = (float)u[x];
    o[x] = (f16)(gg / (1.f + __expf(-gg)) * uu);
  }
  *(f16x4*)(outp + r * (size_t)N + c) = o;
}

// ---------------- final: out += w0*sum_ks eo4[ks][2t] + w1*sum_ks eo4[ks][2t+1]
__global__ void final_add4_kernel(float* __restrict__ outp, const float* __restrict__ eo4,
                                  const float* __restrict__ rw) {
  const size_t i4 = ((size_t)blockIdx.x * 256 + threadIdx.x) * 4;
  const int t = (int)(i4 >> 10);
  const int c = (int)(i4 & 1023);
  const float w0 = rw[2 * t], w1 = rw[2 * t + 1];
  float4 s0 = {0.f, 0.f, 0.f, 0.f}, s1 = {0.f, 0.f, 0.f, 0.f};
#pragma unroll
  for (int ks = 0; ks < 4; ks++) {
    const float* p = eo4 + (size_t)ks * 4096 * 1024;
    float4 a = *(const float4*)(p + (size_t)(2 * t) * 1024 + c);
    float4 b = *(const float4*)(p + (size_t)(2 * t + 1) * 1024 + c);
    s0.x += a.x; s0.y += a.y; s0.z += a.z; s0.w += a.w;
    s1.x += b.x; s1.y += b.y; s1.z += b.z; s1.w += b.w;
  }
  float4 o = *(float4*)(outp + i4);
  o.x += w0 * s0.x + w1 * s1.x;
  o.y += w0 * s0.y + w1 * s1.y;
  o.z += w0 * s0.z + w1 * s1.z;
  o.w += w0 * s0.w + w1 * s1.w;
  *(float4*)(outp + i4) = o;
}

extern "C" void kernel_launch(void* const* d_in, const int* in_sizes, int n_in,
                              void* d_out, int out_size, void* d_ws, size_t ws_size,
                              hipStream_t stream) {
  const int* positions = (const int*)d_in[0];
  const float* hidden = (const float*)d_in[1];
  const float* in_ln = (const float*)d_in[2];
  const float* post_ln = (const float*)d_in[3];
  const float* res_ln = (const float*)d_in[4];
  const float* qkv_w = (const float*)d_in[5];
  const float* o_w = (const float*)d_in[6];
  const float* gate_w = (const float*)d_in[7];
  const float* ws_w = (const float*)d_in[8];
  const float* w2s_w = (const float*)d_in[9];
  const float* w13_w = (const float*)d_in[10];
  const float* w2_w = (const float*)d_in[11];
  float* out = (float*)d_out;

  char* p = (char*)d_ws;
  auto alloc = [&](size_t b) { void* r = (void*)p; p += (b + 255) & ~(size_t)255; return r; };

  f16* wqkv = (f16*)alloc((size_t)1536 * 1024 * 2);
  f16* woh  = (f16*)alloc((size_t)1024 * 1024 * 2);
  f16* wol  = (f16*)alloc((size_t)1024 * 1024 * 2);
  f16* wws  = (f16*)alloc((size_t)8 * 4096 * 1024 * 2);
  f16* ww2  = (f16*)alloc((size_t)8 * 1024 * 2048 * 2);
  f16* w13  = (f16*)alloc((size_t)2048 * 1024 * 2);
  f16* w2c  = (f16*)alloc((size_t)1024 * 1024 * 2);
  f16* hn   = (f16*)alloc((size_t)2048 * 1024 * 2);
  float* qkvp = (float*)alloc((size_t)2 * 2048 * 1536 * 4);  // qkv split partials
  f16* qr = (f16*)alloc((size_t)2048 * 1024 * 2);
  f16* kr = (f16*)alloc((size_t)2048 * 256 * 2);
  f16* vt = (f16*)alloc((size_t)256 * 2048 * 2);
  f16* ath = (f16*)alloc((size_t)2048 * 1024 * 2);
  f16* atl = (f16*)alloc((size_t)2048 * 1024 * 2);
  float* opp = (float*)alloc((size_t)2 * 2048 * 1024 * 4);   // o-proj split partials
  float* resA = (float*)alloc((size_t)2048 * 1024 * 4);
  f16* rn = (f16*)alloc((size_t)2048 * 1024 * 2);
  f16* mn = (f16*)alloc((size_t)2048 * 1024 * 2);
  f16* gu13 = (f16*)alloc((size_t)2048 * 2048 * 2);
  f16* act13 = (f16*)alloc((size_t)2048 * 1024 * 2);
  float* w2p = (float*)alloc((size_t)2 * 2048 * 1024 * 4);   // w2 split partials
  f16* gum = (f16*)alloc((size_t)4096 * 4096 * 2);
  f16* actm = (f16*)alloc((size_t)4096 * 2048 * 2);
  float* eo4 = (float*)alloc((size_t)4 * 4096 * 1024 * 4);   // down-proj split partials
  float* rw = (float*)alloc((size_t)4096 * 4);
  int* counts = (int*)alloc(256);
  int* perm = (int*)alloc((size_t)8 * 2048 * 4);

  // weight conversions (ws is re-poisoned before every timed launch)
  cvt_f16_kernel<<<dim3(1536 * 1024 / 1024), dim3(256), 0, stream>>>(qkv_w, wqkv);
  cvt_f16_kernel<<<dim3(8 * 4096 * 1024 / 1024), dim3(256), 0, stream>>>(ws_w, wws);
  cvt_f16_kernel<<<dim3(8 * 1024 * 2048 / 1024), dim3(256), 0, stream>>>(w2s_w, ww2);
  cvt_f16_kernel<<<dim3(2048 * 1024 / 1024), dim3(256), 0, stream>>>(w13_w, w13);
  cvt_f16_kernel<<<dim3(1024 * 1024 / 1024), dim3(256), 0, stream>>>(w2_w, w2c);
  cvt_f16x2_kernel<<<dim3(1024 * 1024 / 1024), dim3(256), 0, stream>>>(o_w, woh, wol);
  hipMemsetAsync(counts, 0, 256, stream);

  // attention path
  rmsnorm_kernel<<<dim3(512), dim3(256), 0, stream>>>(hidden, in_ln, hn);
  gemm_f16_kernel<0, 64, 2><<<dim3(24, 16, 2), dim3(256), 0, stream>>>(
      hn, wqkv, (void*)qkvp, (const float*)nullptr, 2048, 1536, 1024);
  rope_kernel<<<dim3(3, 2048), dim3(256), 0, stream>>>(qkvp, positions, qr, kr);
  vtrans_kernel<<<dim3(32, 4), dim3(256), 0, stream>>>(qkvp, vt);
  attn_kernel<<<dim3(32, 16), dim3(256), 0, stream>>>(qr, kr, vt, ath, atl);
  gemm_f16x2_add_kernel<2><<<dim3(16, 16, 2), dim3(256), 0, stream>>>(
      ath, atl, woh, wol, opp, (const float*)nullptr, 2048, 1024, 1024);
  add3_kernel<<<dim3(2048), dim3(256), 0, stream>>>(
      resA, hidden, opp, opp + (size_t)2048 * 1024);

  // norms + routing off residual_attn
  rmsnorm_dual_kernel<<<dim3(512), dim3(256), 0, stream>>>(resA, res_ln, post_ln, rn, mn);
  routing_kernel<<<dim3(512), dim3(256), 0, stream>>>(resA, post_ln, gate_w, counts, perm, rw);

  // residual MLP -> d_out holds residual_mlp
  gemm_f16_kernel<2, 64><<<dim3(32, 16), dim3(256), 0, stream>>>(
      rn, w13, (void*)gu13, (const float*)nullptr, 2048, 2048, 1024);
  silu_mul_kernel<<<dim3(2048 * 1024 / 1024), dim3(256), 0, stream>>>(gu13, act13, 10);
  gemm_f16_kernel<0, 64, 2><<<dim3(16, 16, 2), dim3(256), 0, stream>>>(
      act13, w2c, (void*)w2p, (const float*)nullptr, 2048, 1024, 1024);
  add3_kernel<<<dim3(2048), dim3(256), 0, stream>>>(
      out, resA, w2p, w2p + (size_t)2048 * 1024);

  // MoE (top-2 sparse)
  gemm_moe_kernel<1, 128><<<dim3(32, 16, 8), dim3(256), 0, stream>>>(
      mn, wws, (void*)gum, perm, counts, 4096, 1024, (size_t)4096 * 1024);
  silu_mul_kernel<<<dim3(4096 * 2048 / 1024), dim3(256), 0, stream>>>(gum, actm, 11);
  gemm_moe_kernel<0, 128, 4><<<dim3(8, 16, 32), dim3(256), 0, stream>>>(
      actm, ww2, (void*)eo4, perm, counts, 1024, 2048, (size_t)1024 * 2048);
  final_add4_kernel<<<dim3(2048 * 1024 / 1024), dim3(256), 0, stream>>>(out, eo4, rw);
}

// Round 4
// 622.152 us; speedup vs baseline: 1.0452x; 1.0452x over previous
//
#include <hip/hip_runtime.h>
#include <stdint.h>

// ArcticDecoderLayer on MI355X (gfx950).
// Precision plan: f16 MFMA everywhere except (a) o-proj GEMM in f16 hi/lo split
// (3 MFMAs) because its error feeds MoE top-k routing, (b) routing itself in
// fp32, (c) RoPE phases in fp64 (table'd; matches numpy float64 promotion).
// R8: 3-buffer counted-vmcnt GEMM cores (48 KB LDS -> 3 blk/CU). R7's 4-buffer
// (64 KB -> 2 blk/CU) lost more to occupancy than counted vmcnt gained; 2-buffer
// can't count (stage(t+1) must follow the barrier -> degenerates to vmcnt(0)).
// 3 buffers = minimum for counted waits + 1.5x the resident blocks of R7.
// + RoPE phases precomputed once per (t,i) into a 2048x32 table (fp64 work
//   drops 20x; rope_kernel becomes a lookup).
// + down-proj SPLITK 4->2 (partial round-trip halves to 32 MB).
// T=2048 H=1024 NH=16 NKV=4 HD=64 I=2048 E=8 TOPK=2

typedef _Float16 f16;
typedef _Float16 f16x8 __attribute__((ext_vector_type(8)));
typedef _Float16 f16x4 __attribute__((ext_vector_type(4)));
typedef float f32x4 __attribute__((ext_vector_type(4)));

#define DEV __device__ __forceinline__

DEV void glds16(const void* g, void* l) {
  __builtin_amdgcn_global_load_lds((const __attribute__((address_space(1))) void*)g,
                                   (__attribute__((address_space(3))) void*)l, 16, 0, 0);
}

// ---------------- conversions ----------------
__global__ void cvt_f16_kernel(const float* __restrict__ in, f16* __restrict__ outp) {
  const size_t i = ((size_t)blockIdx.x * 256 + threadIdx.x) * 4;
  float4 f = *(const float4*)(in + i);
  f16x4 o;
  o[0] = (f16)f.x; o[1] = (f16)f.y; o[2] = (f16)f.z; o[3] = (f16)f.w;
  *(f16x4*)(outp + i) = o;
}

__global__ void cvt_f16x2_kernel(const float* __restrict__ in,
                                 f16* __restrict__ oh, f16* __restrict__ ol) {
  const size_t i = ((size_t)blockIdx.x * 256 + threadIdx.x) * 4;
  float4 f = *(const float4*)(in + i);
  f16x4 h, l;
  h[0] = (f16)f.x; l[0] = (f16)(f.x - (float)h[0]);
  h[1] = (f16)f.y; l[1] = (f16)(f.y - (float)h[1]);
  h[2] = (f16)f.z; l[2] = (f16)(f.z - (float)h[2]);
  h[3] = (f16)f.w; l[3] = (f16)(f.w - (float)h[3]);
  *(f16x4*)(oh + i) = h;
  *(f16x4*)(ol + i) = l;
}

// ---------------- RMS norms (wave per row, 1024 cols) ----------------
__global__ void rmsnorm_kernel(const float* __restrict__ in, const float* __restrict__ w,
                               f16* __restrict__ outp) {
  const int t = blockIdx.x * 4 + (threadIdx.x >> 6);
  const int lane = threadIdx.x & 63;
  const float* x = in + (size_t)t * 1024;
  float v[16]; float ss = 0.f;
#pragma unroll
  for (int j = 0; j < 16; j++) { float a = x[lane + 64 * j]; v[j] = a; ss += a * a; }
#pragma unroll
  for (int m = 1; m < 64; m <<= 1) ss += __shfl_xor(ss, m);
  const float rs = rsqrtf(ss * (1.f / 1024.f) + 1e-5f);
#pragma unroll
  for (int j = 0; j < 16; j++)
    outp[(size_t)t * 1024 + lane + 64 * j] = (f16)(v[j] * rs * w[lane + 64 * j]);
}

__global__ void rmsnorm_dual_kernel(const float* __restrict__ in,
                                    const float* __restrict__ w1, const float* __restrict__ w2,
                                    f16* __restrict__ o1, f16* __restrict__ o2) {
  const int t = blockIdx.x * 4 + (threadIdx.x >> 6);
  const int lane = threadIdx.x & 63;
  const float* x = in + (size_t)t * 1024;
  float v[16]; float ss = 0.f;
#pragma unroll
  for (int j = 0; j < 16; j++) { float a = x[lane + 64 * j]; v[j] = a; ss += a * a; }
#pragma unroll
  for (int m = 1; m < 64; m <<= 1) ss += __shfl_xor(ss, m);
  const float rs = rsqrtf(ss * (1.f / 1024.f) + 1e-5f);
#pragma unroll
  for (int j = 0; j < 16; j++) {
    float nv = v[j] * rs;
    size_t idx = (size_t)t * 1024 + lane + 64 * j;
    o1[idx] = (f16)(nv * w1[lane + 64 * j]);
    o2[idx] = (f16)(nv * w2[lane + 64 * j]);
  }
}

// ---------------- main GEMM: C[M,N] = A[M,K] * B[N,K]^T, 128xBN x32 tiles ----
// 3-buffer counted-vmcnt pipeline: wait own stage(t) (vmcnt(L), stage(t+1)
// stays in flight), barrier, issue stage(t+2) into buf[(t-1)%3], compute t.
// EPI: 0 = fp32 store, 1 = fp32 store + addsrc, 2 = f16 store
template <int EPI, int BN, int SPLITK = 1>
__global__ __launch_bounds__(256) void gemm_f16_kernel(
    const f16* __restrict__ A, const f16* __restrict__ B,
    void* __restrict__ outp, const float* __restrict__ addsrc,
    int M, int N, int K) {
  constexpr int JT = BN / 32;  // col fragments per wave (wave covers BN/2 cols)
  constexpr int L = (BN == 128) ? 4 : 3;  // glds per thread per K-tile
  __shared__ __attribute__((aligned(16))) f16 As[3][128 * 32];
  __shared__ __attribute__((aligned(16))) f16 Bs[3][BN * 32];
  const int tid = threadIdx.x;
  const size_t row0 = (size_t)blockIdx.y * 128, col0 = (size_t)blockIdx.x * BN;
  const int ks = (SPLITK > 1) ? (int)blockIdx.z : 0;
  const int kspan = K / SPLITK, kb = ks * kspan;
  const int nt = kspan >> 5;
  const int c0 = tid, c1 = tid + 256;
  // pre-swizzled global k-segment: phys seg (tid&3) holds logical seg ^((row>>1)&3)
  const int sw0 = ((c0 & 3) ^ ((c0 >> 3) & 3)) * 8;
  const int sw1 = ((c1 & 3) ^ ((c1 >> 3) & 3)) * 8;
  const f16* a0 = A + (row0 + (c0 >> 2)) * K + sw0;
  const f16* a1 = A + (row0 + (c1 >> 2)) * K + sw1;
  const f16* b0 = B + (col0 + (c0 >> 2)) * K + sw0;
  const f16* b1 = B + (col0 + ((BN == 128) ? (c1 >> 2) : 0)) * K + ((BN == 128) ? sw1 : 0);

  const int wave = tid >> 6, lane = tid & 63, lr = lane >> 4, lc = lane & 15;
  const int wr = wave >> 1, wc = wave & 1;
  const int rsw = (lr ^ ((lc >> 1) & 3)) * 8;  // swizzled read k-offset

  f32x4 acc[4][JT];
#pragma unroll
  for (int i = 0; i < 4; i++)
#pragma unroll
    for (int j = 0; j < JT; j++) acc[i][j] = (f32x4){0.f, 0.f, 0.f, 0.f};

  auto stage = [&](int k0, int buf) {
    glds16(a0 + k0, As[buf] + c0 * 8);
    glds16(a1 + k0, As[buf] + c1 * 8);
    glds16(b0 + k0, Bs[buf] + c0 * 8);
    if constexpr (BN == 128) glds16(b1 + k0, Bs[buf] + c1 * 8);
  };

  stage(kb, 0); stage(kb + 32, 1);
  for (int t = 0; t < nt; ++t) {
    if (t < nt - 1) asm volatile("s_waitcnt vmcnt(%0)" :: "n"(L) : "memory");
    else            asm volatile("s_waitcnt vmcnt(0)" ::: "memory");
    __builtin_amdgcn_s_barrier();
    asm volatile("" ::: "memory");
    if (t + 2 < nt) stage(kb + (t + 2) * 32, (t + 2) % 3);
    const f16* Ab = As[t % 3];
    const f16* Bb = Bs[t % 3];
    f16x8 af[4], bfr[JT];
#pragma unroll
    for (int i = 0; i < 4; i++)
      af[i] = *(const f16x8*)(Ab + (wr * 64 + i * 16 + lc) * 32 + rsw);
#pragma unroll
    for (int j = 0; j < JT; j++)
      bfr[j] = *(const f16x8*)(Bb + (wc * (BN / 2) + j * 16 + lc) * 32 + rsw);
#pragma unroll
    for (int i = 0; i < 4; i++)
#pragma unroll
      for (int j = 0; j < JT; j++)
        acc[i][j] = __builtin_amdgcn_mfma_f32_16x16x32_f16(af[i], bfr[j], acc[i][j], 0, 0, 0);
  }

#pragma unroll
  for (int i = 0; i < 4; i++)
#pragma unroll
    for (int j = 0; j < JT; j++) {
      const size_t rbase = row0 + wr * 64 + i * 16 + lr * 4;
      const size_t col = col0 + wc * (BN / 2) + j * 16 + lc;
#pragma unroll
      for (int r = 0; r < 4; r++) {
        size_t idx = (rbase + r) * N + col;
        if constexpr (SPLITK > 1) {
          ((float*)outp)[(size_t)ks * M * N + idx] = acc[i][j][r];
        } else if constexpr (EPI == 0) ((float*)outp)[idx] = acc[i][j][r];
        else if constexpr (EPI == 1) ((float*)outp)[idx] = acc[i][j][r] + addsrc[idx];
        else ((f16*)outp)[idx] = (f16)acc[i][j][r];
      }
    }
}

// ---------------- o-proj GEMM, f16 hi/lo split (3 MFMAs), 128x64 ------------
// 3-buffer counted-vmcnt (72 KB LDS -> 2 blk/CU).
// SPLITK>1: fp32 partials at outp + ks*M*N (no addsrc; add3 combines).
template <int SPLITK>
__global__ __launch_bounds__(256) void gemm_f16x2_add_kernel(
    const f16* __restrict__ Ah, const f16* __restrict__ Al,
    const f16* __restrict__ Bh, const f16* __restrict__ Bl,
    float* __restrict__ outp, const float* __restrict__ addsrc,
    int M, int N, int K) {
  __shared__ __attribute__((aligned(16))) f16 Ash[3][128 * 32];
  __shared__ __attribute__((aligned(16))) f16 Asl[3][128 * 32];
  __shared__ __attribute__((aligned(16))) f16 Bsh[3][64 * 32];
  __shared__ __attribute__((aligned(16))) f16 Bsl[3][64 * 32];
  const int tid = threadIdx.x;
  const size_t row0 = (size_t)blockIdx.y * 128, col0 = (size_t)blockIdx.x * 64;
  const int ks = (SPLITK > 1) ? (int)blockIdx.z : 0;
  const int kspan = K / SPLITK, kb = ks * kspan;
  const int nt = kspan >> 5;
  const int c0 = tid, c1 = tid + 256;
  const int sw0 = ((c0 & 3) ^ ((c0 >> 3) & 3)) * 8;
  const int sw1 = ((c1 & 3) ^ ((c1 >> 3) & 3)) * 8;
  const size_t aoff0 = (row0 + (c0 >> 2)) * K + sw0;
  const size_t aoff1 = (row0 + (c1 >> 2)) * K + sw1;
  const size_t boff0 = (col0 + (c0 >> 2)) * K + sw0;

  const int wave = tid >> 6, lane = tid & 63, lr = lane >> 4, lc = lane & 15;
  const int wr = wave >> 1, wc = wave & 1;
  const int rsw = (lr ^ ((lc >> 1) & 3)) * 8;

  f32x4 acc[4][2];
#pragma unroll
  for (int i = 0; i < 4; i++)
#pragma unroll
    for (int j = 0; j < 2; j++) acc[i][j] = (f32x4){0.f, 0.f, 0.f, 0.f};

  auto stage = [&](int k0, int buf) {
    glds16(Ah + aoff0 + k0, Ash[buf] + c0 * 8);
    glds16(Ah + aoff1 + k0, Ash[buf] + c1 * 8);
    glds16(Al + aoff0 + k0, Asl[buf] + c0 * 8);
    glds16(Al + aoff1 + k0, Asl[buf] + c1 * 8);
    glds16(Bh + boff0 + k0, Bsh[buf] + c0 * 8);
    glds16(Bl + boff0 + k0, Bsl[buf] + c0 * 8);
  };

  stage(kb, 0); stage(kb + 32, 1);
  for (int t = 0; t < nt; ++t) {
    if (t < nt - 1) asm volatile("s_waitcnt vmcnt(%0)" :: "n"(6) : "memory");
    else            asm volatile("s_waitcnt vmcnt(0)" ::: "memory");
    __builtin_amdgcn_s_barrier();
    asm volatile("" ::: "memory");
    if (t + 2 < nt) stage(kb + (t + 2) * 32, (t + 2) % 3);
    const int bc = t % 3;
    f16x8 afh[4], afl[4], bfh[2], bfl[2];
#pragma unroll
    for (int i = 0; i < 4; i++) {
      const int ro = (wr * 64 + i * 16 + lc) * 32 + rsw;
      afh[i] = *(const f16x8*)(Ash[bc] + ro);
      afl[i] = *(const f16x8*)(Asl[bc] + ro);
    }
#pragma unroll
    for (int j = 0; j < 2; j++) {
      const int ro = (wc * 32 + j * 16 + lc) * 32 + rsw;
      bfh[j] = *(const f16x8*)(Bsh[bc] + ro);
      bfl[j] = *(const f16x8*)(Bsl[bc] + ro);
    }
#pragma unroll
    for (int i = 0; i < 4; i++)
#pragma unroll
      for (int j = 0; j < 2; j++) {
        acc[i][j] = __builtin_amdgcn_mfma_f32_16x16x32_f16(afh[i], bfh[j], acc[i][j], 0, 0, 0);
        acc[i][j] = __builtin_amdgcn_mfma_f32_16x16x32_f16(afh[i], bfl[j], acc[i][j], 0, 0, 0);
        acc[i][j] = __builtin_amdgcn_mfma_f32_16x16x32_f16(afl[i], bfh[j], acc[i][j], 0, 0, 0);
      }
  }

#pragma unroll
  for (int i = 0; i < 4; i++)
#pragma unroll
    for (int j = 0; j < 2; j++) {
      const size_t rbase = row0 + wr * 64 + i * 16 + lr * 4;
      const size_t col = col0 + wc * 32 + j * 16 + lc;
#pragma unroll
      for (int r = 0; r < 4; r++) {
        size_t idx = (rbase + r) * N + col;
        if constexpr (SPLITK > 1) outp[(size_t)ks * M * N + idx] = acc[i][j][r];
        else outp[idx] = acc[i][j][r] + addsrc[idx];
      }
    }
}

// ---------------- MoE GEMM: gathered A rows via perm, per-expert B -----------
// DIVROW=1: A row = sid>>1 (token) ; DIVROW=0: A row = sid (slot)
// A staged via per-lane-address glds (gather rows clamped to 0; garbage rows
// are row-local in MFMA and never stored). 3-buffer counted pipeline.
// SPLITK>1: blockIdx.z = e*SPLITK + ks; fp32 partials at outp + ks*4096*N.
template <int DIVROW, int BN, int SPLITK = 1>
__global__ __launch_bounds__(256) void gemm_moe_kernel(
    const f16* __restrict__ A, const f16* __restrict__ Ball, void* __restrict__ outp,
    const int* __restrict__ perm, const int* __restrict__ counts,
    int N, int K, size_t strideB) {
  constexpr int JT = BN / 32;
  constexpr int L = (BN == 128) ? 4 : 3;
  const int e = (int)blockIdx.z / SPLITK;
  const int ks = (int)blockIdx.z % SPLITK;
  const int cnt = counts[e];
  const int bm = blockIdx.y;
  if (bm * 128 >= cnt) return;
  const int kspan = K / SPLITK, kb = ks * kspan;
  const int nt = kspan >> 5;
  const f16* B = Ball + (size_t)e * strideB;
  __shared__ __attribute__((aligned(16))) f16 As[3][128 * 32];
  __shared__ __attribute__((aligned(16))) f16 Bs[3][BN * 32];
  const int tid = threadIdx.x;
  const size_t col0 = (size_t)blockIdx.x * BN;
  const int c0 = tid, c1 = tid + 256;
  const int pbase = e * 2048 + bm * 128;
  const int rt0 = c0 >> 2, rt1 = c1 >> 2;
  const int sid0 = (bm * 128 + rt0 < cnt) ? perm[pbase + rt0] : 0;
  const int sid1 = (bm * 128 + rt1 < cnt) ? perm[pbase + rt1] : 0;
  const size_t ar0 = DIVROW ? (size_t)(sid0 >> 1) : (size_t)sid0;
  const size_t ar1 = DIVROW ? (size_t)(sid1 >> 1) : (size_t)sid1;
  const int sw0 = ((c0 & 3) ^ ((c0 >> 3) & 3)) * 8;
  const int sw1 = ((c1 & 3) ^ ((c1 >> 3) & 3)) * 8;
  const f16* ap0 = A + ar0 * K + sw0;
  const f16* ap1 = A + ar1 * K + sw1;
  const f16* b0 = B + (col0 + (c0 >> 2)) * K + sw0;
  const f16* b1 = B + (col0 + ((BN == 128) ? (c1 >> 2) : 0)) * K + ((BN == 128) ? sw1 : 0);

  const int wave = tid >> 6, lane = tid & 63, lr = lane >> 4, lc = lane & 15;
  const int wr = wave >> 1, wc = wave & 1;
  const int rsw = (lr ^ ((lc >> 1) & 3)) * 8;

  f32x4 acc[4][JT];
#pragma unroll
  for (int i = 0; i < 4; i++)
#pragma unroll
    for (int j = 0; j < JT; j++) acc[i][j] = (f32x4){0.f, 0.f, 0.f, 0.f};

  auto stage = [&](int k0, int buf) {
    glds16(ap0 + k0, As[buf] + c0 * 8);
    glds16(ap1 + k0, As[buf] + c1 * 8);
    glds16(b0 + k0, Bs[buf] + c0 * 8);
    if constexpr (BN == 128) glds16(b1 + k0, Bs[buf] + c1 * 8);
  };

  stage(kb, 0); stage(kb + 32, 1);
  for (int t = 0; t < nt; ++t) {
    if (t < nt - 1) asm volatile("s_waitcnt vmcnt(%0)" :: "n"(L) : "memory");
    else            asm volatile("s_waitcnt vmcnt(0)" ::: "memory");
    __builtin_amdgcn_s_barrier();
    asm volatile("" ::: "memory");
    if (t + 2 < nt) stage(kb + (t + 2) * 32, (t + 2) % 3);
    const f16* Ab = As[t % 3];
    const f16* Bb = Bs[t % 3];
    f16x8 af[4], bfr[JT];
#pragma unroll
    for (int i = 0; i < 4; i++)
      af[i] = *(const f16x8*)(Ab + (wr * 64 + i * 16 + lc) * 32 + rsw);
#pragma unroll
    for (int j = 0; j < JT; j++)
      bfr[j] = *(const f16x8*)(Bb + (wc * (BN / 2) + j * 16 + lc) * 32 + rsw);
#pragma unroll
    for (int i = 0; i < 4; i++)
#pragma unroll
      for (int j = 0; j < JT; j++)
        acc[i][j] = __builtin_amdgcn_mfma_f32_16x16x32_f16(af[i], bfr[j], acc[i][j], 0, 0, 0);
  }

  int sids[4][4];
#pragma unroll
  for (int i = 0; i < 4; i++)
#pragma unroll
    for (int r = 0; r < 4; r++) {
      int rit = wr * 64 + i * 16 + lr * 4 + r;
      sids[i][r] = (bm * 128 + rit < cnt) ? perm[pbase + rit] : -1;
    }
#pragma unroll
  for (int i = 0; i < 4; i++)
#pragma unroll
    for (int j = 0; j < JT; j++) {
      const size_t col = col0 + wc * (BN / 2) + j * 16 + lc;
#pragma unroll
      for (int r = 0; r < 4; r++)
        if (sids[i][r] >= 0) {
          if constexpr (SPLITK > 1)
            ((float*)outp)[((size_t)ks * 4096 + sids[i][r]) * N + col] = acc[i][j][r];
          else
            ((f16*)outp)[(size_t)sids[i][r] * N + col] = (f16)acc[i][j][r];
        }
    }
}

// ---------------- RoPE phase table: (t,i) -> (cos,sin), fp64 once -----------
__global__ void rope_table_kernel(const int* __restrict__ pos, float2* __restrict__ tab) {
  const int idx = blockIdx.x * 256 + threadIdx.x;  // 0..65535
  const int t = idx >> 5, i = idx & 31;
  const double ph = (double)pos[t] * exp((double)i * -0.28782313662425575);  // ln(1e4)/32
  tab[idx] = make_float2((float)cos(ph), (float)sin(ph));
}

// ---------------- RoPE: table lookup, reads qkv split partials (sum) --------
__global__ void rope_kernel(const float* __restrict__ qkv, const float2* __restrict__ tab,
                            f16* __restrict__ qr, f16* __restrict__ kr) {
  const int t = blockIdx.y;
  const int u = blockIdx.x * 256 + threadIdx.x;  // 0..767, use 0..639
  if (u >= 640) return;
  const float* b0 = qkv + (size_t)t * 1536;
  const float* b1 = b0 + (size_t)2048 * 1536;
  const int head = u >> 5, i = u & 31;
  const bool isq = head < 16;
  const int off = isq ? head * 64 + i : 1024 + (head - 16) * 64 + i;
  const float x1 = b0[off] + b1[off], x2 = b0[off + 32] + b1[off + 32];
  const float2 cs = tab[t * 32 + i];
  const float c = cs.x, s = cs.y;
  const float r1 = x1 * c - x2 * s, r2 = x2 * c + x1 * s;
  if (isq) {
    // 0.125 * log2(e): base-2 softmax in attn
    const float qs = 0.18033688011116042f;
    qr[(size_t)t * 1024 + head * 64 + i] = (f16)(qs * r1);
    qr[(size_t)t * 1024 + head * 64 + i + 32] = (f16)(qs * r2);
  } else {
    const int kh = head - 16;
    kr[(size_t)t * 256 + kh * 64 + i] = (f16)r1;
    kr[(size_t)t * 256 + kh * 64 + i + 32] = (f16)r2;
  }
}

// ---------------- V transpose from qkv split partials (sum) -----------------
__global__ void vtrans_kernel(const float* __restrict__ qkvf, f16* __restrict__ vt) {
  __shared__ float Ts[64 * 69];
  const int t0 = blockIdx.x * 64;
  const int kv = blockIdx.y;
  const int tid = threadIdx.x;
  const int tr = tid >> 2, jj = tid & 3;
  const float* src0 = qkvf + (size_t)(t0 + tr) * 1536 + 1280 + kv * 64 + jj * 16;
  const float* src1 = src0 + (size_t)2048 * 1536;
#pragma unroll
  for (int x = 0; x < 4; x++) {
    float4 f = *(const float4*)(src0 + x * 4);
    float4 g = *(const float4*)(src1 + x * 4);
    Ts[tr * 69 + jj * 16 + x * 4 + 0] = f.x + g.x;
    Ts[tr * 69 + jj * 16 + x * 4 + 1] = f.y + g.y;
    Ts[tr * 69 + jj * 16 + x * 4 + 2] = f.z + g.z;
    Ts[tr * 69 + jj * 16 + x * 4 + 3] = f.w + g.w;
  }
  __syncthreads();
  f16* dst = vt + (size_t)(kv * 64 + tr) * 2048 + t0 + jj * 16;
#pragma unroll
  for (int x = 0; x < 2; x++) {
    f16x8 o;
#pragma unroll
    for (int i = 0; i < 8; i++) o[i] = (f16)Ts[(jj * 16 + x * 8 + i) * 69 + tr];
    *(f16x8*)(dst + x * 8) = o;
  }
}

// ---------------- add3: o = a + p0 + p1 (fp32, deterministic combine) -------
__global__ void add3_kernel(float* __restrict__ o, const float* __restrict__ a,
                            const float* __restrict__ p0, const float* __restrict__ p1) {
  const size_t i4 = ((size_t)blockIdx.x * 256 + threadIdx.x) * 4;
  float4 va = *(const float4*)(a + i4);
  float4 v0 = *(const float4*)(p0 + i4);
  float4 v1 = *(const float4*)(p1 + i4);
  va.x += v0.x + v1.x;
  va.y += v0.y + v1.y;
  va.z += v0.z + v1.z;
  va.w += v0.w + v1.w;
  *(float4*)(o + i4) = va;
}

// ---------------- flash attention v4: S^T = K*Q^T + LDS-staged K/V ----------
// 4 waves/block, each wave 16 q-rows (block = 64). K,V^T staged per 128-chunk
// into padded LDS (stride 72 / 136 f16 -> conflict-free b128 access). Next-chunk
// global loads prefetched into VGPRs during compute. 52 KB LDS -> 3 blk/CU.
__global__ __launch_bounds__(256, 3) void attn_kernel(
    const f16* __restrict__ qr, const f16* __restrict__ kr, const f16* __restrict__ vt,
    f16* __restrict__ ahi, f16* __restrict__ alo) {
  const int qt = 31 - (int)blockIdx.x;  // 64-row q tiles, heavy first
  const int h = blockIdx.y;
  const int kvh = h >> 2;
  __shared__ __attribute__((aligned(16))) f16 Ks[128 * 72];   // [k=128][d=64 +8pad]
  __shared__ __attribute__((aligned(16))) f16 Vs[64 * 136];   // [d=64][k=128 +8pad]
  __shared__ __attribute__((aligned(16))) f16 Pl[4 * 16 * 136];  // per-wave P^T strips
  const int tid = threadIdx.x;
  const int wave = tid >> 6, lane = tid & 63, lr = lane >> 4, lc = lane & 15;
  const int trow = qt * 64 + wave * 16 + lc;  // this lane's q row (S^T column)
  f16* Pw = Pl + wave * 16 * 136;

  // staging roles (whole block)
  const int krow = tid >> 3, kcol = (tid & 7) * 8;    // 32 k-rows per iter, 4 iters
  const int vrow = tid >> 4, vcol = (tid & 15) * 8;   // 16 d-rows per iter, 4 iters
  const f16* kgbase = kr + (size_t)kvh * 64 + kcol;
  const f16* vgbase = vt + (size_t)(kvh * 64 + vrow) * 2048 + vcol;

  // Q as B-operand: B[n=lc=t][k=d]
  const f16* qp = qr + (size_t)trow * 1024 + h * 64 + lr * 8;
  f16x8 qf0 = *(const f16x8*)(qp);
  f16x8 qf1 = *(const f16x8*)(qp + 32);

  float m_run = -3e38f, l_run = 0.f;
  f32x4 accO[4];
#pragma unroll
  for (int jo = 0; jo < 4; jo++) accO[jo] = (f32x4){0.f, 0.f, 0.f, 0.f};

  const int nch = (qt >> 1) + 1;  // 128-wide chunks

  f16x8 kreg[4], vreg[4];
  // preload chunk 0
#pragma unroll
  for (int it = 0; it < 4; it++) {
    kreg[it] = *(const f16x8*)(kgbase + (size_t)(it * 32 + krow) * 256);
    vreg[it] = *(const f16x8*)(vgbase + it * 16 * 2048);
  }

  for (int ch = 0; ch < nch; ++ch) {
    const int c0 = ch * 128;
    const bool last = (ch == nch - 1);

    __syncthreads();  // previous chunk's LDS reads complete
#pragma unroll
    for (int it = 0; it < 4; it++) {
      *(f16x8*)(Ks + (it * 32 + krow) * 72 + kcol) = kreg[it];
      *(f16x8*)(Vs + (it * 16 + vrow) * 136 + vcol) = vreg[it];
    }
    __syncthreads();  // staging visible

    // prefetch next chunk into regs (overlaps with compute below)
    if (!last) {
      const int c1 = c0 + 128;
#pragma unroll
      for (int it = 0; it < 4; it++) {
        kreg[it] = *(const f16x8*)(kgbase + (size_t)(c1 + it * 32 + krow) * 256);
        vreg[it] = *(const f16x8*)(vgbase + it * 16 * 2048 + c1);
      }
    }

    // ---- S^T tiles: A = K rows from LDS, B = Q frag ----
    f32x4 st[8];
#pragma unroll
    for (int j = 0; j < 8; j++) {
      const f16* kp = Ks + (j * 16 + lc) * 72 + lr * 8;
      f16x8 ka0 = *(const f16x8*)(kp);
      f16x8 ka1 = *(const f16x8*)(kp + 32);
      f32x4 s = (f32x4){0.f, 0.f, 0.f, 0.f};
      s = __builtin_amdgcn_mfma_f32_16x16x32_f16(ka0, qf0, s, 0, 0, 0);
      s = __builtin_amdgcn_mfma_f32_16x16x32_f16(ka1, qf1, s, 0, 0, 0);
      st[j] = s;
    }

    // ---- causal mask (only last chunk crosses the diagonal) ----
    if (last) {
#pragma unroll
      for (int j = 0; j < 8; j++)
#pragma unroll
        for (int r = 0; r < 4; r++)
          if (c0 + j * 16 + lr * 4 + r > trow) st[j][r] = -3e38f;
    }

    // ---- chunk max: in-lane over 32 regs + 2 shuffles ----
    float mc = -3e38f;
#pragma unroll
    for (int j = 0; j < 8; j++)
      mc = fmaxf(mc, fmaxf(fmaxf(st[j][0], st[j][1]), fmaxf(st[j][2], st[j][3])));
    mc = fmaxf(mc, __shfl_xor(mc, 16));
    mc = fmaxf(mc, __shfl_xor(mc, 32));
    const float mn = fmaxf(m_run, mc);
    const float alpha = __builtin_amdgcn_exp2f(m_run - mn);
    m_run = mn;

    // ---- exp2, packed P^T stores (b64, 2-way = free), in-lane sum ----
    float ls = 0.f;
#pragma unroll
    for (int j = 0; j < 8; j++) {
      f16x4 pv;
#pragma unroll
      for (int r = 0; r < 4; r++) {
        float e = __builtin_amdgcn_exp2f(st[j][r] - mn);
        ls += e;
        pv[r] = (f16)e;
      }
      *(f16x4*)(Pw + lc * 136 + j * 16 + lr * 4) = pv;  // P^T[t=lc][s]
    }
    ls += __shfl_xor(ls, 16);
    ls += __shfl_xor(ls, 32);
    l_run = l_run * alpha + ls;
#pragma unroll
    for (int jo = 0; jo < 4; jo++) accO[jo] *= alpha;

    // ---- O^T += V^T * P^T : A = V^T frags (LDS), B = P^T (wave-private) ----
#pragma unroll
    for (int kkt = 0; kkt < 4; kkt++) {
      f16x8 pb = *(const f16x8*)(Pw + lc * 136 + kkt * 32 + lr * 8);
#pragma unroll
      for (int jo = 0; jo < 4; jo++) {
        f16x8 va = *(const f16x8*)(Vs + (jo * 16 + lc) * 136 + kkt * 32 + lr * 8);
        accO[jo] = __builtin_amdgcn_mfma_f32_16x16x32_f16(va, pb, accO[jo], 0, 0, 0);
      }
    }
  }

  // ---- epilogue: O^T lane holds col t, rows d = jo*16+lr*4+r ----
  const float inv = 1.f / l_run;
#pragma unroll
  for (int jo = 0; jo < 4; jo++) {
    f16x4 hi4, lo4;
#pragma unroll
    for (int r = 0; r < 4; r++) {
      float o = accO[jo][r] * inv;
      f16 hv = (f16)o;
      hi4[r] = hv;
      lo4[r] = (f16)(o - (float)hv);
    }
    const size_t idx = (size_t)trow * 1024 + h * 64 + jo * 16 + lr * 4;
    *(f16x4*)(ahi + idx) = hi4;
    *(f16x4*)(alo + idx) = lo4;
  }
}

// ---------------- routing: fp32 norm + gate + top2, compaction --------------
__global__ void routing_kernel(const float* __restrict__ resA,
                               const float* __restrict__ postw,
                               const float* __restrict__ gw,
                               int* __restrict__ counts, int* __restrict__ perm,
                               float* __restrict__ rw) {
  const int t = blockIdx.x * 4 + (threadIdx.x >> 6);
  const int lane = threadIdx.x & 63;
  const float* x = resA + (size_t)t * 1024;
  float v[16]; float ss = 0.f;
#pragma unroll
  for (int j = 0; j < 16; j++) { float a = x[lane + 64 * j]; v[j] = a; ss += a * a; }
#pragma unroll
  for (int m = 1; m < 64; m <<= 1) ss += __shfl_xor(ss, m);
  const float rs = rsqrtf(ss * (1.f / 1024.f) + 1e-5f);
#pragma unroll
  for (int j = 0; j < 16; j++) v[j] *= rs * postw[lane + 64 * j];
  float lg[8];
#pragma unroll
  for (int e = 0; e < 8; e++) {
    float p = 0.f;
    const float* g = gw + (size_t)e * 1024;
#pragma unroll
    for (int j = 0; j < 16; j++) p += v[j] * g[lane + 64 * j];
#pragma unroll
    for (int m = 1; m < 64; m <<= 1) p += __shfl_xor(p, m);
    lg[e] = p;
  }
  if (lane == 0) {
    int e0 = 0; float b0 = lg[0];
#pragma unroll
    for (int e = 1; e < 8; e++) if (lg[e] > b0) { b0 = lg[e]; e0 = e; }
    int e1 = -1; float b1 = -3e38f;
#pragma unroll
    for (int e = 0; e < 8; e++) if (e != e0 && lg[e] > b1) { b1 = lg[e]; e1 = e; }
    const float w0 = 1.f / (1.f + expf(b1 - b0));  // p0/(p0+p1)
    const float w1 = 1.f - w0;
    int p0 = atomicAdd(&counts[e0], 1);
    perm[e0 * 2048 + p0] = t * 2;
    int p1 = atomicAdd(&counts[e1], 1);
    perm[e1 * 2048 + p1] = t * 2 + 1;
    rw[t * 2] = w0;
    rw[t * 2 + 1] = w1;
  }
}

// ---------------- silu(g)*u ----------------
__global__ void silu_mul_kernel(const f16* __restrict__ gu, f16* __restrict__ outp, int lgN) {
  const int N = 1 << lgN;
  const size_t i4 = ((size_t)blockIdx.x * 256 + threadIdx.x) * 4;
  const size_t r = i4 >> lgN;
  const int c = (int)(i4 & (N - 1));
  const f16* gp = gu + r * (size_t)(2 * N) + c;
  f16x4 g = *(const f16x4*)gp;
  f16x4 u = *(const f16x4*)(gp + N);
  f16x4 o;
#pragma unroll
  for (int x = 0; x < 4; x++) {
    float gg = (float)g[x], uu = (float)u[x];
    o[x] = (f16)(gg / (1.f + __expf(-gg)) * uu);
  }
  *(f16x4*)(outp + r * (size_t)N + c) = o;
}

// ---------------- final: out += w0*sum_ks eo2[ks][2t] + w1*sum_ks eo2[ks][2t+1]
__global__ void final_add2_kernel(float* __restrict__ outp, const float* __restrict__ eo2,
                                  const float* __restrict__ rw) {
  const size_t i4 = ((size_t)blockIdx.x * 256 + threadIdx.x) * 4;
  const int t = (int)(i4 >> 10);
  const int c = (int)(i4 & 1023);
  const float w0 = rw[2 * t], w1 = rw[2 * t + 1];
  float4 s0 = {0.f, 0.f, 0.f, 0.f}, s1 = {0.f, 0.f, 0.f, 0.f};
#pragma unroll
  for (int ks = 0; ks < 2; ks++) {
    const float* p = eo2 + (size_t)ks * 4096 * 1024;
    float4 a = *(const float4*)(p + (size_t)(2 * t) * 1024 + c);
    float4 b = *(const float4*)(p + (size_t)(2 * t + 1) * 1024 + c);
    s0.x += a.x; s0.y += a.y; s0.z += a.z; s0.w += a.w;
    s1.x += b.x; s1.y += b.y; s1.z += b.z; s1.w += b.w;
  }
  float4 o = *(float4*)(outp + i4);
  o.x += w0 * s0.x + w1 * s1.x;
  o.y += w0 * s0.y + w1 * s1.y;
  o.z += w0 * s0.z + w1 * s1.z;
  o.w += w0 * s0.w + w1 * s1.w;
  *(float4*)(outp + i4) = o;
}

extern "C" void kernel_launch(void* const* d_in, const int* in_sizes, int n_in,
                              void* d_out, int out_size, void* d_ws, size_t ws_size,
                              hipStream_t stream) {
  const int* positions = (const int*)d_in[0];
  const float* hidden = (const float*)d_in[1];
  const float* in_ln = (const float*)d_in[2];
  const float* post_ln = (const float*)d_in[3];
  const float* res_ln = (const float*)d_in[4];
  const float* qkv_w = (const float*)d_in[5];
  const float* o_w = (const float*)d_in[6];
  const float* gate_w = (const float*)d_in[7];
  const float* ws_w = (const float*)d_in[8];
  const float* w2s_w = (const float*)d_in[9];
  const float* w13_w = (const float*)d_in[10];
  const float* w2_w = (const float*)d_in[11];
  float* out = (float*)d_out;

  char* p = (char*)d_ws;
  auto alloc = [&](size_t b) { void* r = (void*)p; p += (b + 255) & ~(size_t)255; return r; };

  f16* wqkv = (f16*)alloc((size_t)1536 * 1024 * 2);
  f16* woh  = (f16*)alloc((size_t)1024 * 1024 * 2);
  f16* wol  = (f16*)alloc((size_t)1024 * 1024 * 2);
  f16* wws  = (f16*)alloc((size_t)8 * 4096 * 1024 * 2);
  f16* ww2  = (f16*)alloc((size_t)8 * 1024 * 2048 * 2);
  f16* w13  = (f16*)alloc((size_t)2048 * 1024 * 2);
  f16* w2c  = (f16*)alloc((size_t)1024 * 1024 * 2);
  f16* hn   = (f16*)alloc((size_t)2048 * 1024 * 2);
  float* qkvp = (float*)alloc((size_t)2 * 2048 * 1536 * 4);  // qkv split partials
  float2* ptab = (float2*)alloc((size_t)2048 * 32 * 8);      // rope phase table
  f16* qr = (f16*)alloc((size_t)2048 * 1024 * 2);
  f16* kr = (f16*)alloc((size_t)2048 * 256 * 2);
  f16* vt = (f16*)alloc((size_t)256 * 2048 * 2);
  f16* ath = (f16*)alloc((size_t)2048 * 1024 * 2);
  f16* atl = (f16*)alloc((size_t)2048 * 1024 * 2);
  float* opp = (float*)alloc((size_t)2 * 2048 * 1024 * 4);   // o-proj split partials
  float* resA = (float*)alloc((size_t)2048 * 1024 * 4);
  f16* rn = (f16*)alloc((size_t)2048 * 1024 * 2);
  f16* mn = (f16*)alloc((size_t)2048 * 1024 * 2);
  f16* gu13 = (f16*)alloc((size_t)2048 * 2048 * 2);
  f16* act13 = (f16*)alloc((size_t)2048 * 1024 * 2);
  float* w2p = (float*)alloc((size_t)2 * 2048 * 1024 * 4);   // w2 split partials
  f16* gum = (f16*)alloc((size_t)4096 * 4096 * 2);
  f16* actm = (f16*)alloc((size_t)4096 * 2048 * 2);
  float* eo2 = (float*)alloc((size_t)2 * 4096 * 1024 * 4);   // down-proj split partials
  float* rw = (float*)alloc((size_t)4096 * 4);
  int* counts = (int*)alloc(256);
  int* perm = (int*)alloc((size_t)8 * 2048 * 4);

  // weight conversions (ws is re-poisoned before every timed launch)
  cvt_f16_kernel<<<dim3(1536 * 1024 / 1024), dim3(256), 0, stream>>>(qkv_w, wqkv);
  cvt_f16_kernel<<<dim3(8 * 4096 * 1024 / 1024), dim3(256), 0, stream>>>(ws_w, wws);
  cvt_f16_kernel<<<dim3(8 * 1024 * 2048 / 1024), dim3(256), 0, stream>>>(w2s_w, ww2);
  cvt_f16_kernel<<<dim3(2048 * 1024 / 1024), dim3(256), 0, stream>>>(w13_w, w13);
  cvt_f16_kernel<<<dim3(1024 * 1024 / 1024), dim3(256), 0, stream>>>(w2_w, w2c);
  cvt_f16x2_kernel<<<dim3(1024 * 1024 / 1024), dim3(256), 0, stream>>>(o_w, woh, wol);
  rope_table_kernel<<<dim3(256), dim3(256), 0, stream>>>(positions, ptab);
  hipMemsetAsync(counts, 0, 256, stream);

  // attention path
  rmsnorm_kernel<<<dim3(512), dim3(256), 0, stream>>>(hidden, in_ln, hn);
  gemm_f16_kernel<0, 64, 2><<<dim3(24, 16, 2), dim3(256), 0, stream>>>(
      hn, wqkv, (void*)qkvp, (const float*)nullptr, 2048, 1536, 1024);
  rope_kernel<<<dim3(3, 2048), dim3(256), 0, stream>>>(qkvp, ptab, qr, kr);
  vtrans_kernel<<<dim3(32, 4), dim3(256), 0, stream>>>(qkvp, vt);
  attn_kernel<<<dim3(32, 16), dim3(256), 0, stream>>>(qr, kr, vt, ath, atl);
  gemm_f16x2_add_kernel<2><<<dim3(16, 16, 2), dim3(256), 0, stream>>>(
      ath, atl, woh, wol, opp, (const float*)nullptr, 2048, 1024, 1024);
  add3_kernel<<<dim3(2048), dim3(256), 0, stream>>>(
      resA, hidden, opp, opp + (size_t)2048 * 1024);

  // norms + routing off residual_attn
  rmsnorm_dual_kernel<<<dim3(512), dim3(256), 0, stream>>>(resA, res_ln, post_ln, rn, mn);
  routing_kernel<<<dim3(512), dim3(256), 0, stream>>>(resA, post_ln, gate_w, counts, perm, rw);

  // residual MLP -> d_out holds residual_mlp
  gemm_f16_kernel<2, 64><<<dim3(32, 16), dim3(256), 0, stream>>>(
      rn, w13, (void*)gu13, (const float*)nullptr, 2048, 2048, 1024);
  silu_mul_kernel<<<dim3(2048 * 1024 / 1024), dim3(256), 0, stream>>>(gu13, act13, 10);
  gemm_f16_kernel<0, 64, 2><<<dim3(16, 16, 2), dim3(256), 0, stream>>>(
      act13, w2c, (void*)w2p, (const float*)nullptr, 2048, 1024, 1024);
  add3_kernel<<<dim3(2048), dim3(256), 0, stream>>>(
      out, resA, w2p, w2p + (size_t)2048 * 1024);

  // MoE (top-2 sparse)
  gemm_moe_kernel<1, 128><<<dim3(32, 16, 8), dim3(256), 0, stream>>>(
      mn, wws, (void*)gum, perm, counts, 4096, 1024, (size_t)4096 * 1024);
  silu_mul_kernel<<<dim3(4096 * 2048 / 1024), dim3(256), 0, stream>>>(gum, actm, 11);
  gemm_moe_kernel<0, 128, 2><<<dim3(8, 16, 16), dim3(256), 0, stream>>>(
      actm, ww2, (void*)eo2, perm, counts, 1024, 2048, (size_t)1024 * 2048);
  final_add2_kernel<<<dim3(2048 * 1024 / 1024), dim3(256), 0, stream>>>(out, eo2, rw);
}

// Round 5
// 611.572 us; speedup vs baseline: 1.0633x; 1.0173x over previous
//
#include <hip/hip_runtime.h>
#include <stdint.h>

// ArcticDecoderLayer on MI355X (gfx950).
// Precision plan: f16 MFMA everywhere except (a) o-proj GEMM in f16 hi/lo split
// (3 MFMAs) because its error feeds MoE top-k routing, (b) routing itself in
// fp32, (c) RoPE phases in fp64 (table'd; matches numpy float64 promotion).
// R9: gated MoE up-proj — block stages gate panel (ws rows col0..+64) AND up
// panel (rows 2048+col0..+64) against one A-tile, dual accumulators, epilogue
// writes silu(g)*u directly to actm. Kills the 4096x4096 gum round-trip
// (~100 MB HBM + a launch). GEMM cores stay R8's 3-buffer counted-vmcnt
// pipeline (48 KB LDS -> 3 blk/CU). + s_setprio around MFMA clusters in the
// MoE GEMMs and attention (T5; resident blocks sit at different K-steps).
// T=2048 H=1024 NH=16 NKV=4 HD=64 I=2048 E=8 TOPK=2

typedef _Float16 f16;
typedef _Float16 f16x8 __attribute__((ext_vector_type(8)));
typedef _Float16 f16x4 __attribute__((ext_vector_type(4)));
typedef float f32x4 __attribute__((ext_vector_type(4)));

#define DEV __device__ __forceinline__

DEV void glds16(const void* g, void* l) {
  __builtin_amdgcn_global_load_lds((const __attribute__((address_space(1))) void*)g,
                                   (__attribute__((address_space(3))) void*)l, 16, 0, 0);
}

// ---------------- conversions ----------------
__global__ void cvt_f16_kernel(const float* __restrict__ in, f16* __restrict__ outp) {
  const size_t i = ((size_t)blockIdx.x * 256 + threadIdx.x) * 4;
  float4 f = *(const float4*)(in + i);
  f16x4 o;
  o[0] = (f16)f.x; o[1] = (f16)f.y; o[2] = (f16)f.z; o[3] = (f16)f.w;
  *(f16x4*)(outp + i) = o;
}

__global__ void cvt_f16x2_kernel(const float* __restrict__ in,
                                 f16* __restrict__ oh, f16* __restrict__ ol) {
  const size_t i = ((size_t)blockIdx.x * 256 + threadIdx.x) * 4;
  float4 f = *(const float4*)(in + i);
  f16x4 h, l;
  h[0] = (f16)f.x; l[0] = (f16)(f.x - (float)h[0]);
  h[1] = (f16)f.y; l[1] = (f16)(f.y - (float)h[1]);
  h[2] = (f16)f.z; l[2] = (f16)(f.z - (float)h[2]);
  h[3] = (f16)f.w; l[3] = (f16)(f.w - (float)h[3]);
  *(f16x4*)(oh + i) = h;
  *(f16x4*)(ol + i) = l;
}

// ---------------- RMS norms (wave per row, 1024 cols) ----------------
__global__ void rmsnorm_kernel(const float* __restrict__ in, const float* __restrict__ w,
                               f16* __restrict__ outp) {
  const int t = blockIdx.x * 4 + (threadIdx.x >> 6);
  const int lane = threadIdx.x & 63;
  const float* x = in + (size_t)t * 1024;
  float v[16]; float ss = 0.f;
#pragma unroll
  for (int j = 0; j < 16; j++) { float a = x[lane + 64 * j]; v[j] = a; ss += a * a; }
#pragma unroll
  for (int m = 1; m < 64; m <<= 1) ss += __shfl_xor(ss, m);
  const float rs = rsqrtf(ss * (1.f / 1024.f) + 1e-5f);
#pragma unroll
  for (int j = 0; j < 16; j++)
    outp[(size_t)t * 1024 + lane + 64 * j] = (f16)(v[j] * rs * w[lane + 64 * j]);
}

__global__ void rmsnorm_dual_kernel(const float* __restrict__ in,
                                    const float* __restrict__ w1, const float* __restrict__ w2,
                                    f16* __restrict__ o1, f16* __restrict__ o2) {
  const int t = blockIdx.x * 4 + (threadIdx.x >> 6);
  const int lane = threadIdx.x & 63;
  const float* x = in + (size_t)t * 1024;
  float v[16]; float ss = 0.f;
#pragma unroll
  for (int j = 0; j < 16; j++) { float a = x[lane + 64 * j]; v[j] = a; ss += a * a; }
#pragma unroll
  for (int m = 1; m < 64; m <<= 1) ss += __shfl_xor(ss, m);
  const float rs = rsqrtf(ss * (1.f / 1024.f) + 1e-5f);
#pragma unroll
  for (int j = 0; j < 16; j++) {
    float nv = v[j] * rs;
    size_t idx = (size_t)t * 1024 + lane + 64 * j;
    o1[idx] = (f16)(nv * w1[lane + 64 * j]);
    o2[idx] = (f16)(nv * w2[lane + 64 * j]);
  }
}

// ---------------- main GEMM: C[M,N] = A[M,K] * B[N,K]^T, 128xBN x32 tiles ----
// 3-buffer counted-vmcnt pipeline: wait own stage(t) (vmcnt(L), stage(t+1)
// stays in flight), barrier, issue stage(t+2) into buf[(t-1)%3], compute t.
// EPI: 0 = fp32 store, 1 = fp32 store + addsrc, 2 = f16 store
template <int EPI, int BN, int SPLITK = 1>
__global__ __launch_bounds__(256) void gemm_f16_kernel(
    const f16* __restrict__ A, const f16* __restrict__ B,
    void* __restrict__ outp, const float* __restrict__ addsrc,
    int M, int N, int K) {
  constexpr int JT = BN / 32;  // col fragments per wave (wave covers BN/2 cols)
  constexpr int L = (BN == 128) ? 4 : 3;  // glds per thread per K-tile
  __shared__ __attribute__((aligned(16))) f16 As[3][128 * 32];
  __shared__ __attribute__((aligned(16))) f16 Bs[3][BN * 32];
  const int tid = threadIdx.x;
  const size_t row0 = (size_t)blockIdx.y * 128, col0 = (size_t)blockIdx.x * BN;
  const int ks = (SPLITK > 1) ? (int)blockIdx.z : 0;
  const int kspan = K / SPLITK, kb = ks * kspan;
  const int nt = kspan >> 5;
  const int c0 = tid, c1 = tid + 256;
  // pre-swizzled global k-segment: phys seg (tid&3) holds logical seg ^((row>>1)&3)
  const int sw0 = ((c0 & 3) ^ ((c0 >> 3) & 3)) * 8;
  const int sw1 = ((c1 & 3) ^ ((c1 >> 3) & 3)) * 8;
  const f16* a0 = A + (row0 + (c0 >> 2)) * K + sw0;
  const f16* a1 = A + (row0 + (c1 >> 2)) * K + sw1;
  const f16* b0 = B + (col0 + (c0 >> 2)) * K + sw0;
  const f16* b1 = B + (col0 + ((BN == 128) ? (c1 >> 2) : 0)) * K + ((BN == 128) ? sw1 : 0);

  const int wave = tid >> 6, lane = tid & 63, lr = lane >> 4, lc = lane & 15;
  const int wr = wave >> 1, wc = wave & 1;
  const int rsw = (lr ^ ((lc >> 1) & 3)) * 8;  // swizzled read k-offset

  f32x4 acc[4][JT];
#pragma unroll
  for (int i = 0; i < 4; i++)
#pragma unroll
    for (int j = 0; j < JT; j++) acc[i][j] = (f32x4){0.f, 0.f, 0.f, 0.f};

  auto stage = [&](int k0, int buf) {
    glds16(a0 + k0, As[buf] + c0 * 8);
    glds16(a1 + k0, As[buf] + c1 * 8);
    glds16(b0 + k0, Bs[buf] + c0 * 8);
    if constexpr (BN == 128) glds16(b1 + k0, Bs[buf] + c1 * 8);
  };

  stage(kb, 0); stage(kb + 32, 1);
  for (int t = 0; t < nt; ++t) {
    if (t < nt - 1) asm volatile("s_waitcnt vmcnt(%0)" :: "n"(L) : "memory");
    else            asm volatile("s_waitcnt vmcnt(0)" ::: "memory");
    __builtin_amdgcn_s_barrier();
    asm volatile("" ::: "memory");
    if (t + 2 < nt) stage(kb + (t + 2) * 32, (t + 2) % 3);
    const f16* Ab = As[t % 3];
    const f16* Bb = Bs[t % 3];
    f16x8 af[4], bfr[JT];
#pragma unroll
    for (int i = 0; i < 4; i++)
      af[i] = *(const f16x8*)(Ab + (wr * 64 + i * 16 + lc) * 32 + rsw);
#pragma unroll
    for (int j = 0; j < JT; j++)
      bfr[j] = *(const f16x8*)(Bb + (wc * (BN / 2) + j * 16 + lc) * 32 + rsw);
#pragma unroll
    for (int i = 0; i < 4; i++)
#pragma unroll
      for (int j = 0; j < JT; j++)
        acc[i][j] = __builtin_amdgcn_mfma_f32_16x16x32_f16(af[i], bfr[j], acc[i][j], 0, 0, 0);
  }

#pragma unroll
  for (int i = 0; i < 4; i++)
#pragma unroll
    for (int j = 0; j < JT; j++) {
      const size_t rbase = row0 + wr * 64 + i * 16 + lr * 4;
      const size_t col = col0 + wc * (BN / 2) + j * 16 + lc;
#pragma unroll
      for (int r = 0; r < 4; r++) {
        size_t idx = (rbase + r) * N + col;
        if constexpr (SPLITK > 1) {
          ((float*)outp)[(size_t)ks * M * N + idx] = acc[i][j][r];
        } else if constexpr (EPI == 0) ((float*)outp)[idx] = acc[i][j][r];
        else if constexpr (EPI == 1) ((float*)outp)[idx] = acc[i][j][r] + addsrc[idx];
        else ((f16*)outp)[idx] = (f16)acc[i][j][r];
      }
    }
}

// ---------------- o-proj GEMM, f16 hi/lo split (3 MFMAs), 128x64 ------------
// 3-buffer counted-vmcnt (72 KB LDS -> 2 blk/CU).
// SPLITK>1: fp32 partials at outp + ks*M*N (no addsrc; add3 combines).
template <int SPLITK>
__global__ __launch_bounds__(256) void gemm_f16x2_add_kernel(
    const f16* __restrict__ Ah, const f16* __restrict__ Al,
    const f16* __restrict__ Bh, const f16* __restrict__ Bl,
    float* __restrict__ outp, const float* __restrict__ addsrc,
    int M, int N, int K) {
  __shared__ __attribute__((aligned(16))) f16 Ash[3][128 * 32];
  __shared__ __attribute__((aligned(16))) f16 Asl[3][128 * 32];
  __shared__ __attribute__((aligned(16))) f16 Bsh[3][64 * 32];
  __shared__ __attribute__((aligned(16))) f16 Bsl[3][64 * 32];
  const int tid = threadIdx.x;
  const size_t row0 = (size_t)blockIdx.y * 128, col0 = (size_t)blockIdx.x * 64;
  const int ks = (SPLITK > 1) ? (int)blockIdx.z : 0;
  const int kspan = K / SPLITK, kb = ks * kspan;
  const int nt = kspan >> 5;
  const int c0 = tid, c1 = tid + 256;
  const int sw0 = ((c0 & 3) ^ ((c0 >> 3) & 3)) * 8;
  const int sw1 = ((c1 & 3) ^ ((c1 >> 3) & 3)) * 8;
  const size_t aoff0 = (row0 + (c0 >> 2)) * K + sw0;
  const size_t aoff1 = (row0 + (c1 >> 2)) * K + sw1;
  const size_t boff0 = (col0 + (c0 >> 2)) * K + sw0;

  const int wave = tid >> 6, lane = tid & 63, lr = lane >> 4, lc = lane & 15;
  const int wr = wave >> 1, wc = wave & 1;
  const int rsw = (lr ^ ((lc >> 1) & 3)) * 8;

  f32x4 acc[4][2];
#pragma unroll
  for (int i = 0; i < 4; i++)
#pragma unroll
    for (int j = 0; j < 2; j++) acc[i][j] = (f32x4){0.f, 0.f, 0.f, 0.f};

  auto stage = [&](int k0, int buf) {
    glds16(Ah + aoff0 + k0, Ash[buf] + c0 * 8);
    glds16(Ah + aoff1 + k0, Ash[buf] + c1 * 8);
    glds16(Al + aoff0 + k0, Asl[buf] + c0 * 8);
    glds16(Al + aoff1 + k0, Asl[buf] + c1 * 8);
    glds16(Bh + boff0 + k0, Bsh[buf] + c0 * 8);
    glds16(Bl + boff0 + k0, Bsl[buf] + c0 * 8);
  };

  stage(kb, 0); stage(kb + 32, 1);
  for (int t = 0; t < nt; ++t) {
    if (t < nt - 1) asm volatile("s_waitcnt vmcnt(%0)" :: "n"(6) : "memory");
    else            asm volatile("s_waitcnt vmcnt(0)" ::: "memory");
    __builtin_amdgcn_s_barrier();
    asm volatile("" ::: "memory");
    if (t + 2 < nt) stage(kb + (t + 2) * 32, (t + 2) % 3);
    const int bc = t % 3;
    f16x8 afh[4], afl[4], bfh[2], bfl[2];
#pragma unroll
    for (int i = 0; i < 4; i++) {
      const int ro = (wr * 64 + i * 16 + lc) * 32 + rsw;
      afh[i] = *(const f16x8*)(Ash[bc] + ro);
      afl[i] = *(const f16x8*)(Asl[bc] + ro);
    }
#pragma unroll
    for (int j = 0; j < 2; j++) {
      const int ro = (wc * 32 + j * 16 + lc) * 32 + rsw;
      bfh[j] = *(const f16x8*)(Bsh[bc] + ro);
      bfl[j] = *(const f16x8*)(Bsl[bc] + ro);
    }
#pragma unroll
    for (int i = 0; i < 4; i++)
#pragma unroll
      for (int j = 0; j < 2; j++) {
        acc[i][j] = __builtin_amdgcn_mfma_f32_16x16x32_f16(afh[i], bfh[j], acc[i][j], 0, 0, 0);
        acc[i][j] = __builtin_amdgcn_mfma_f32_16x16x32_f16(afh[i], bfl[j], acc[i][j], 0, 0, 0);
        acc[i][j] = __builtin_amdgcn_mfma_f32_16x16x32_f16(afl[i], bfh[j], acc[i][j], 0, 0, 0);
      }
  }

#pragma unroll
  for (int i = 0; i < 4; i++)
#pragma unroll
    for (int j = 0; j < 2; j++) {
      const size_t rbase = row0 + wr * 64 + i * 16 + lr * 4;
      const size_t col = col0 + wc * 32 + j * 16 + lc;
#pragma unroll
      for (int r = 0; r < 4; r++) {
        size_t idx = (rbase + r) * N + col;
        if constexpr (SPLITK > 1) outp[(size_t)ks * M * N + idx] = acc[i][j][r];
        else outp[idx] = acc[i][j][r] + addsrc[idx];
      }
    }
}

// ---------------- gated MoE up-proj: actm[sid] = silu(A*Bg^T) * (A*Bu^T) -----
// Block: A-tile 128 gathered rows x K32, Bg = ws rows [col0,col0+64),
// Bu = ws rows [2048+col0, +64). Dual accumulators, 16 MFMA/K-step, L=4,
// 48 KB LDS -> 3 blk/CU. Epilogue applies silu on fp32 and writes f16 actm.
__global__ __launch_bounds__(256) void gemm_moe_gated_kernel(
    const f16* __restrict__ A, const f16* __restrict__ Ball, f16* __restrict__ actm,
    const int* __restrict__ perm, const int* __restrict__ counts,
    int K, size_t strideB) {
  const int e = (int)blockIdx.z;
  const int cnt = counts[e];
  const int bm = blockIdx.y;
  if (bm * 128 >= cnt) return;
  const int nt = K >> 5;
  const f16* B = Ball + (size_t)e * strideB;
  __shared__ __attribute__((aligned(16))) f16 As[3][128 * 32];
  __shared__ __attribute__((aligned(16))) f16 Bgs[3][64 * 32];
  __shared__ __attribute__((aligned(16))) f16 Bus[3][64 * 32];
  const int tid = threadIdx.x;
  const size_t col0 = (size_t)blockIdx.x * 64;
  const int c0 = tid, c1 = tid + 256;
  const int pbase = e * 2048 + bm * 128;
  const int rt0 = c0 >> 2, rt1 = c1 >> 2;
  const int sid0 = (bm * 128 + rt0 < cnt) ? perm[pbase + rt0] : 0;
  const int sid1 = (bm * 128 + rt1 < cnt) ? perm[pbase + rt1] : 0;
  const size_t ar0 = (size_t)(sid0 >> 1);  // token row
  const size_t ar1 = (size_t)(sid1 >> 1);
  const int sw0 = ((c0 & 3) ^ ((c0 >> 3) & 3)) * 8;
  const int sw1 = ((c1 & 3) ^ ((c1 >> 3) & 3)) * 8;
  const f16* ap0 = A + ar0 * K + sw0;
  const f16* ap1 = A + ar1 * K + sw1;
  const f16* bg0 = B + (col0 + (c0 >> 2)) * K + sw0;
  const f16* bu0 = B + (2048 + col0 + (c0 >> 2)) * K + sw0;

  const int wave = tid >> 6, lane = tid & 63, lr = lane >> 4, lc = lane & 15;
  const int wr = wave >> 1, wc = wave & 1;
  const int rsw = (lr ^ ((lc >> 1) & 3)) * 8;

  f32x4 accg[4][2], accu[4][2];
#pragma unroll
  for (int i = 0; i < 4; i++)
#pragma unroll
    for (int j = 0; j < 2; j++) {
      accg[i][j] = (f32x4){0.f, 0.f, 0.f, 0.f};
      accu[i][j] = (f32x4){0.f, 0.f, 0.f, 0.f};
    }

  auto stage = [&](int k0, int buf) {
    glds16(ap0 + k0, As[buf] + c0 * 8);
    glds16(ap1 + k0, As[buf] + c1 * 8);
    glds16(bg0 + k0, Bgs[buf] + c0 * 8);
    glds16(bu0 + k0, Bus[buf] + c0 * 8);
  };

  stage(0, 0); stage(32, 1);
  for (int t = 0; t < nt; ++t) {
    if (t < nt - 1) asm volatile("s_waitcnt vmcnt(%0)" :: "n"(4) : "memory");
    else            asm volatile("s_waitcnt vmcnt(0)" ::: "memory");
    __builtin_amdgcn_s_barrier();
    asm volatile("" ::: "memory");
    if (t + 2 < nt) stage((t + 2) * 32, (t + 2) % 3);
    const f16* Ab = As[t % 3];
    const f16* Bgb = Bgs[t % 3];
    const f16* Bub = Bus[t % 3];
    f16x8 af[4], bg[2], bu[2];
#pragma unroll
    for (int i = 0; i < 4; i++)
      af[i] = *(const f16x8*)(Ab + (wr * 64 + i * 16 + lc) * 32 + rsw);
#pragma unroll
    for (int j = 0; j < 2; j++) {
      const int ro = (wc * 32 + j * 16 + lc) * 32 + rsw;
      bg[j] = *(const f16x8*)(Bgb + ro);
      bu[j] = *(const f16x8*)(Bub + ro);
    }
    __builtin_amdgcn_s_setprio(1);
#pragma unroll
    for (int i = 0; i < 4; i++)
#pragma unroll
      for (int j = 0; j < 2; j++) {
        accg[i][j] = __builtin_amdgcn_mfma_f32_16x16x32_f16(af[i], bg[j], accg[i][j], 0, 0, 0);
        accu[i][j] = __builtin_amdgcn_mfma_f32_16x16x32_f16(af[i], bu[j], accu[i][j], 0, 0, 0);
      }
    __builtin_amdgcn_s_setprio(0);
  }

  int sids[4][4];
#pragma unroll
  for (int i = 0; i < 4; i++)
#pragma unroll
    for (int r = 0; r < 4; r++) {
      int rit = wr * 64 + i * 16 + lr * 4 + r;
      sids[i][r] = (bm * 128 + rit < cnt) ? perm[pbase + rit] : -1;
    }
#pragma unroll
  for (int i = 0; i < 4; i++)
#pragma unroll
    for (int j = 0; j < 2; j++) {
      const size_t col = col0 + wc * 32 + j * 16 + lc;
#pragma unroll
      for (int r = 0; r < 4; r++)
        if (sids[i][r] >= 0) {
          const float g = accg[i][j][r], u = accu[i][j][r];
          actm[(size_t)sids[i][r] * 2048 + col] = (f16)(g / (1.f + __expf(-g)) * u);
        }
    }
}

// ---------------- MoE GEMM: gathered A rows via perm, per-expert B -----------
// DIVROW=1: A row = sid>>1 (token) ; DIVROW=0: A row = sid (slot)
// A staged via per-lane-address glds (gather rows clamped to 0; garbage rows
// are row-local in MFMA and never stored). 3-buffer counted pipeline.
// SPLITK>1: blockIdx.z = e*SPLITK + ks; fp32 partials at outp + ks*4096*N.
template <int DIVROW, int BN, int SPLITK = 1>
__global__ __launch_bounds__(256) void gemm_moe_kernel(
    const f16* __restrict__ A, const f16* __restrict__ Ball, void* __restrict__ outp,
    const int* __restrict__ perm, const int* __restrict__ counts,
    int N, int K, size_t strideB) {
  constexpr int JT = BN / 32;
  constexpr int L = (BN == 128) ? 4 : 3;
  const int e = (int)blockIdx.z / SPLITK;
  const int ks = (int)blockIdx.z % SPLITK;
  const int cnt = counts[e];
  const int bm = blockIdx.y;
  if (bm * 128 >= cnt) return;
  const int kspan = K / SPLITK, kb = ks * kspan;
  const int nt = kspan >> 5;
  const f16* B = Ball + (size_t)e * strideB;
  __shared__ __attribute__((aligned(16))) f16 As[3][128 * 32];
  __shared__ __attribute__((aligned(16))) f16 Bs[3][BN * 32];
  const int tid = threadIdx.x;
  const size_t col0 = (size_t)blockIdx.x * BN;
  const int c0 = tid, c1 = tid + 256;
  const int pbase = e * 2048 + bm * 128;
  const int rt0 = c0 >> 2, rt1 = c1 >> 2;
  const int sid0 = (bm * 128 + rt0 < cnt) ? perm[pbase + rt0] : 0;
  const int sid1 = (bm * 128 + rt1 < cnt) ? perm[pbase + rt1] : 0;
  const size_t ar0 = DIVROW ? (size_t)(sid0 >> 1) : (size_t)sid0;
  const size_t ar1 = DIVROW ? (size_t)(sid1 >> 1) : (size_t)sid1;
  const int sw0 = ((c0 & 3) ^ ((c0 >> 3) & 3)) * 8;
  const int sw1 = ((c1 & 3) ^ ((c1 >> 3) & 3)) * 8;
  const f16* ap0 = A + ar0 * K + sw0;
  const f16* ap1 = A + ar1 * K + sw1;
  const f16* b0 = B + (col0 + (c0 >> 2)) * K + sw0;
  const f16* b1 = B + (col0 + ((BN == 128) ? (c1 >> 2) : 0)) * K + ((BN == 128) ? sw1 : 0);

  const int wave = tid >> 6, lane = tid & 63, lr = lane >> 4, lc = lane & 15;
  const int wr = wave >> 1, wc = wave & 1;
  const int rsw = (lr ^ ((lc >> 1) & 3)) * 8;

  f32x4 acc[4][JT];
#pragma unroll
  for (int i = 0; i < 4; i++)
#pragma unroll
    for (int j = 0; j < JT; j++) acc[i][j] = (f32x4){0.f, 0.f, 0.f, 0.f};

  auto stage = [&](int k0, int buf) {
    glds16(ap0 + k0, As[buf] + c0 * 8);
    glds16(ap1 + k0, As[buf] + c1 * 8);
    glds16(b0 + k0, Bs[buf] + c0 * 8);
    if constexpr (BN == 128) glds16(b1 + k0, Bs[buf] + c1 * 8);
  };

  stage(kb, 0); stage(kb + 32, 1);
  for (int t = 0; t < nt; ++t) {
    if (t < nt - 1) asm volatile("s_waitcnt vmcnt(%0)" :: "n"(L) : "memory");
    else            asm volatile("s_waitcnt vmcnt(0)" ::: "memory");
    __builtin_amdgcn_s_barrier();
    asm volatile("" ::: "memory");
    if (t + 2 < nt) stage(kb + (t + 2) * 32, (t + 2) % 3);
    const f16* Ab = As[t % 3];
    const f16* Bb = Bs[t % 3];
    f16x8 af[4], bfr[JT];
#pragma unroll
    for (int i = 0; i < 4; i++)
      af[i] = *(const f16x8*)(Ab + (wr * 64 + i * 16 + lc) * 32 + rsw);
#pragma unroll
    for (int j = 0; j < JT; j++)
      bfr[j] = *(const f16x8*)(Bb + (wc * (BN / 2) + j * 16 + lc) * 32 + rsw);
    __builtin_amdgcn_s_setprio(1);
#pragma unroll
    for (int i = 0; i < 4; i++)
#pragma unroll
      for (int j = 0; j < JT; j++)
        acc[i][j] = __builtin_amdgcn_mfma_f32_16x16x32_f16(af[i], bfr[j], acc[i][j], 0, 0, 0);
    __builtin_amdgcn_s_setprio(0);
  }

  int sids[4][4];
#pragma unroll
  for (int i = 0; i < 4; i++)
#pragma unroll
    for (int r = 0; r < 4; r++) {
      int rit = wr * 64 + i * 16 + lr * 4 + r;
      sids[i][r] = (bm * 128 + rit < cnt) ? perm[pbase + rit] : -1;
    }
#pragma unroll
  for (int i = 0; i < 4; i++)
#pragma unroll
    for (int j = 0; j < JT; j++) {
      const size_t col = col0 + wc * (BN / 2) + j * 16 + lc;
#pragma unroll
      for (int r = 0; r < 4; r++)
        if (sids[i][r] >= 0) {
          if constexpr (SPLITK > 1)
            ((float*)outp)[((size_t)ks * 4096 + sids[i][r]) * N + col] = acc[i][j][r];
          else
            ((f16*)outp)[(size_t)sids[i][r] * N + col] = (f16)acc[i][j][r];
        }
    }
}

// ---------------- RoPE phase table: (t,i) -> (cos,sin), fp64 once -----------
__global__ void rope_table_kernel(const int* __restrict__ pos, float2* __restrict__ tab) {
  const int idx = blockIdx.x * 256 + threadIdx.x;  // 0..65535
  const int t = idx >> 5, i = idx & 31;
  const double ph = (double)pos[t] * exp((double)i * -0.28782313662425575);  // ln(1e4)/32
  tab[idx] = make_float2((float)cos(ph), (float)sin(ph));
}

// ---------------- RoPE: table lookup, reads qkv split partials (sum) --------
__global__ void rope_kernel(const float* __restrict__ qkv, const float2* __restrict__ tab,
                            f16* __restrict__ qr, f16* __restrict__ kr) {
  const int t = blockIdx.y;
  const int u = blockIdx.x * 256 + threadIdx.x;  // 0..767, use 0..639
  if (u >= 640) return;
  const float* b0 = qkv + (size_t)t * 1536;
  const float* b1 = b0 + (size_t)2048 * 1536;
  const int head = u >> 5, i = u & 31;
  const bool isq = head < 16;
  const int off = isq ? head * 64 + i : 1024 + (head - 16) * 64 + i;
  const float x1 = b0[off] + b1[off], x2 = b0[off + 32] + b1[off + 32];
  const float2 cs = tab[t * 32 + i];
  const float c = cs.x, s = cs.y;
  const float r1 = x1 * c - x2 * s, r2 = x2 * c + x1 * s;
  if (isq) {
    // 0.125 * log2(e): base-2 softmax in attn
    const float qs = 0.18033688011116042f;
    qr[(size_t)t * 1024 + head * 64 + i] = (f16)(qs * r1);
    qr[(size_t)t * 1024 + head * 64 + i + 32] = (f16)(qs * r2);
  } else {
    const int kh = head - 16;
    kr[(size_t)t * 256 + kh * 64 + i] = (f16)r1;
    kr[(size_t)t * 256 + kh * 64 + i + 32] = (f16)r2;
  }
}

// ---------------- V transpose from qkv split partials (sum) -----------------
__global__ void vtrans_kernel(const float* __restrict__ qkvf, f16* __restrict__ vt) {
  __shared__ float Ts[64 * 69];
  const int t0 = blockIdx.x * 64;
  const int kv = blockIdx.y;
  const int tid = threadIdx.x;
  const int tr = tid >> 2, jj = tid & 3;
  const float* src0 = qkvf + (size_t)(t0 + tr) * 1536 + 1280 + kv * 64 + jj * 16;
  const float* src1 = src0 + (size_t)2048 * 1536;
#pragma unroll
  for (int x = 0; x < 4; x++) {
    float4 f = *(const float4*)(src0 + x * 4);
    float4 g = *(const float4*)(src1 + x * 4);
    Ts[tr * 69 + jj * 16 + x * 4 + 0] = f.x + g.x;
    Ts[tr * 69 + jj * 16 + x * 4 + 1] = f.y + g.y;
    Ts[tr * 69 + jj * 16 + x * 4 + 2] = f.z + g.z;
    Ts[tr * 69 + jj * 16 + x * 4 + 3] = f.w + g.w;
  }
  __syncthreads();
  f16* dst = vt + (size_t)(kv * 64 + tr) * 2048 + t0 + jj * 16;
#pragma unroll
  for (int x = 0; x < 2; x++) {
    f16x8 o;
#pragma unroll
    for (int i = 0; i < 8; i++) o[i] = (f16)Ts[(jj * 16 + x * 8 + i) * 69 + tr];
    *(f16x8*)(dst + x * 8) = o;
  }
}

// ---------------- add3: o = a + p0 + p1 (fp32, deterministic combine) -------
__global__ void add3_kernel(float* __restrict__ o, const float* __restrict__ a,
                            const float* __restrict__ p0, const float* __restrict__ p1) {
  const size_t i4 = ((size_t)blockIdx.x * 256 + threadIdx.x) * 4;
  float4 va = *(const float4*)(a + i4);
  float4 v0 = *(const float4*)(p0 + i4);
  float4 v1 = *(const float4*)(p1 + i4);
  va.x += v0.x + v1.x;
  va.y += v0.y + v1.y;
  va.z += v0.z + v1.z;
  va.w += v0.w + v1.w;
  *(float4*)(o + i4) = va;
}

// ---------------- flash attention v4: S^T = K*Q^T + LDS-staged K/V ----------
// 4 waves/block, each wave 16 q-rows (block = 64). K,V^T staged per 128-chunk
// into padded LDS (stride 72 / 136 f16 -> conflict-free b128 access). Next-chunk
// global loads prefetched into VGPRs during compute. 52 KB LDS -> 3 blk/CU.
__global__ __launch_bounds__(256, 3) void attn_kernel(
    const f16* __restrict__ qr, const f16* __restrict__ kr, const f16* __restrict__ vt,
    f16* __restrict__ ahi, f16* __restrict__ alo) {
  const int qt = 31 - (int)blockIdx.x;  // 64-row q tiles, heavy first
  const int h = blockIdx.y;
  const int kvh = h >> 2;
  __shared__ __attribute__((aligned(16))) f16 Ks[128 * 72];   // [k=128][d=64 +8pad]
  __shared__ __attribute__((aligned(16))) f16 Vs[64 * 136];   // [d=64][k=128 +8pad]
  __shared__ __attribute__((aligned(16))) f16 Pl[4 * 16 * 136];  // per-wave P^T strips
  const int tid = threadIdx.x;
  const int wave = tid >> 6, lane = tid & 63, lr = lane >> 4, lc = lane & 15;
  const int trow = qt * 64 + wave * 16 + lc;  // this lane's q row (S^T column)
  f16* Pw = Pl + wave * 16 * 136;

  // staging roles (whole block)
  const int krow = tid >> 3, kcol = (tid & 7) * 8;    // 32 k-rows per iter, 4 iters
  const int vrow = tid >> 4, vcol = (tid & 15) * 8;   // 16 d-rows per iter, 4 iters
  const f16* kgbase = kr + (size_t)kvh * 64 + kcol;
  const f16* vgbase = vt + (size_t)(kvh * 64 + vrow) * 2048 + vcol;

  // Q as B-operand: B[n=lc=t][k=d]
  const f16* qp = qr + (size_t)trow * 1024 + h * 64 + lr * 8;
  f16x8 qf0 = *(const f16x8*)(qp);
  f16x8 qf1 = *(const f16x8*)(qp + 32);

  float m_run = -3e38f, l_run = 0.f;
  f32x4 accO[4];
#pragma unroll
  for (int jo = 0; jo < 4; jo++) accO[jo] = (f32x4){0.f, 0.f, 0.f, 0.f};

  const int nch = (qt >> 1) + 1;  // 128-wide chunks

  f16x8 kreg[4], vreg[4];
  // preload chunk 0
#pragma unroll
  for (int it = 0; it < 4; it++) {
    kreg[it] = *(const f16x8*)(kgbase + (size_t)(it * 32 + krow) * 256);
    vreg[it] = *(const f16x8*)(vgbase + it * 16 * 2048);
  }

  for (int ch = 0; ch < nch; ++ch) {
    const int c0 = ch * 128;
    const bool last = (ch == nch - 1);

    __syncthreads();  // previous chunk's LDS reads complete
#pragma unroll
    for (int it = 0; it < 4; it++) {
      *(f16x8*)(Ks + (it * 32 + krow) * 72 + kcol) = kreg[it];
      *(f16x8*)(Vs + (it * 16 + vrow) * 136 + vcol) = vreg[it];
    }
    __syncthreads();  // staging visible

    // prefetch next chunk into regs (overlaps with compute below)
    if (!last) {
      const int c1 = c0 + 128;
#pragma unroll
      for (int it = 0; it < 4; it++) {
        kreg[it] = *(const f16x8*)(kgbase + (size_t)(c1 + it * 32 + krow) * 256);
        vreg[it] = *(const f16x8*)(vgbase + it * 16 * 2048 + c1);
      }
    }

    // ---- S^T tiles: A = K rows from LDS, B = Q frag ----
    f32x4 st[8];
    __builtin_amdgcn_s_setprio(1);
#pragma unroll
    for (int j = 0; j < 8; j++) {
      const f16* kp = Ks + (j * 16 + lc) * 72 + lr * 8;
      f16x8 ka0 = *(const f16x8*)(kp);
      f16x8 ka1 = *(const f16x8*)(kp + 32);
      f32x4 s = (f32x4){0.f, 0.f, 0.f, 0.f};
      s = __builtin_amdgcn_mfma_f32_16x16x32_f16(ka0, qf0, s, 0, 0, 0);
      s = __builtin_amdgcn_mfma_f32_16x16x32_f16(ka1, qf1, s, 0, 0, 0);
      st[j] = s;
    }
    __builtin_amdgcn_s_setprio(0);

    // ---- causal mask (only last chunk crosses the diagonal) ----
    if (last) {
#pragma unroll
      for (int j = 0; j < 8; j++)
#pragma unroll
        for (int r = 0; r < 4; r++)
          if (c0 + j * 16 + lr * 4 + r > trow) st[j][r] = -3e38f;
    }

    // ---- chunk max: in-lane over 32 regs + 2 shuffles ----
    float mc = -3e38f;
#pragma unroll
    for (int j = 0; j < 8; j++)
      mc = fmaxf(mc, fmaxf(fmaxf(st[j][0], st[j][1]), fmaxf(st[j][2], st[j][3])));
    mc = fmaxf(mc, __shfl_xor(mc, 16));
    mc = fmaxf(mc, __shfl_xor(mc, 32));
    const float mn = fmaxf(m_run, mc);
    const float alpha = __builtin_amdgcn_exp2f(m_run - mn);
    m_run = mn;

    // ---- exp2, packed P^T stores (b64, 2-way = free), in-lane sum ----
    float ls = 0.f;
#pragma unroll
    for (int j = 0; j < 8; j++) {
      f16x4 pv;
#pragma unroll
      for (int r = 0; r < 4; r++) {
        float e = __builtin_amdgcn_exp2f(st[j][r] - mn);
        ls += e;
        pv[r] = (f16)e;
      }
      *(f16x4*)(Pw + lc * 136 + j * 16 + lr * 4) = pv;  // P^T[t=lc][s]
    }
    ls += __shfl_xor(ls, 16);
    ls += __shfl_xor(ls, 32);
    l_run = l_run * alpha + ls;
#pragma unroll
    for (int jo = 0; jo < 4; jo++) accO[jo] *= alpha;

    // ---- O^T += V^T * P^T : A = V^T frags (LDS), B = P^T (wave-private) ----
    __builtin_amdgcn_s_setprio(1);
#pragma unroll
    for (int kkt = 0; kkt < 4; kkt++) {
      f16x8 pb = *(const f16x8*)(Pw + lc * 136 + kkt * 32 + lr * 8);
#pragma unroll
      for (int jo = 0; jo < 4; jo++) {
        f16x8 va = *(const f16x8*)(Vs + (jo * 16 + lc) * 136 + kkt * 32 + lr * 8);
        accO[jo] = __builtin_amdgcn_mfma_f32_16x16x32_f16(va, pb, accO[jo], 0, 0, 0);
      }
    }
    __builtin_amdgcn_s_setprio(0);
  }

  // ---- epilogue: O^T lane holds col t, rows d = jo*16+lr*4+r ----
  const float inv = 1.f / l_run;
#pragma unroll
  for (int jo = 0; jo < 4; jo++) {
    f16x4 hi4, lo4;
#pragma unroll
    for (int r = 0; r < 4; r++) {
      float o = accO[jo][r] * inv;
      f16 hv = (f16)o;
      hi4[r] = hv;
      lo4[r] = (f16)(o - (float)hv);
    }
    const size_t idx = (size_t)trow * 1024 + h * 64 + jo * 16 + lr * 4;
    *(f16x4*)(ahi + idx) = hi4;
    *(f16x4*)(alo + idx) = lo4;
  }
}

// ---------------- routing: fp32 norm + gate + top2, compaction --------------
__global__ void routing_kernel(const float* __restrict__ resA,
                               const float* __restrict__ postw,
                               const float* __restrict__ gw,
                               int* __restrict__ counts, int* __restrict__ perm,
                               float* __restrict__ rw) {
  const int t = blockIdx.x * 4 + (threadIdx.x >> 6);
  const int lane = threadIdx.x & 63;
  const float* x = resA + (size_t)t * 1024;
  float v[16]; float ss = 0.f;
#pragma unroll
  for (int j = 0; j < 16; j++) { float a = x[lane + 64 * j]; v[j] = a; ss += a * a; }
#pragma unroll
  for (int m = 1; m < 64; m <<= 1) ss += __shfl_xor(ss, m);
  const float rs = rsqrtf(ss * (1.f / 1024.f) + 1e-5f);
#pragma unroll
  for (int j = 0; j < 16; j++) v[j] *= rs * postw[lane + 64 * j];
  float lg[8];
#pragma unroll
  for (int e = 0; e < 8; e++) {
    float p = 0.f;
    const float* g = gw + (size_t)e * 1024;
#pragma unroll
    for (int j = 0; j < 16; j++) p += v[j] * g[lane + 64 * j];
#pragma unroll
    for (int m = 1; m < 64; m <<= 1) p += __shfl_xor(p, m);
    lg[e] = p;
  }
  if (lane == 0) {
    int e0 = 0; float b0 = lg[0];
#pragma unroll
    for (int e = 1; e < 8; e++) if (lg[e] > b0) { b0 = lg[e]; e0 = e; }
    int e1 = -1; float b1 = -3e38f;
#pragma unroll
    for (int e = 0; e < 8; e++) if (e != e0 && lg[e] > b1) { b1 = lg[e]; e1 = e; }
    const float w0 = 1.f / (1.f + expf(b1 - b0));  // p0/(p0+p1)
    const float w1 = 1.f - w0;
    int p0 = atomicAdd(&counts[e0], 1);
    perm[e0 * 2048 + p0] = t * 2;
    int p1 = atomicAdd(&counts[e1], 1);
    perm[e1 * 2048 + p1] = t * 2 + 1;
    rw[t * 2] = w0;
    rw[t * 2 + 1] = w1;
  }
}

// ---------------- silu(g)*u ----------------
__global__ void silu_mul_kernel(const f16* __restrict__ gu, f16* __restrict__ outp, int lgN) {
  const int N = 1 << lgN;
  const size_t i4 = ((size_t)blockIdx.x * 256 + threadIdx.x) * 4;
  const size_t r = i4 >> lgN;
  const int c = (int)(i4 & (N - 1));
  const f16* gp = gu + r * (size_t)(2 * N) + c;
  f16x4 g = *(const f16x4*)gp;
  f16x4 u = *(const f16x4*)(gp + N);
  f16x4 o;
#pragma unroll
  for (int x = 0; x < 4; x++) {
    float gg = (float)g[x], uu = (float)u[x];
    o[x] = (f16)(gg / (1.f + __expf(-gg)) * uu);
  }
  *(f16x4*)(outp + r * (size_t)N + c) = o;
}

// ---------------- final: out += w0*sum_ks eo2[ks][2t] + w1*sum_ks eo2[ks][2t+1]
__global__ void final_add2_kernel(float* __restrict__ outp, const float* __restrict__ eo2,
                                  const float* __restrict__ rw) {
  const size_t i4 = ((size_t)blockIdx.x * 256 + threadIdx.x) * 4;
  const int t = (int)(i4 >> 10);
  const int c = (int)(i4 & 1023);
  const float w0 = rw[2 * t], w1 = rw[2 * t + 1];
  float4 s0 = {0.f, 0.f, 0.f, 0.f}, s1 = {0.f, 0.f, 0.f, 0.f};
#pragma unroll
  for (int ks = 0; ks < 2; ks++) {
    const float* p = eo2 + (size_t)ks * 4096 * 1024;
    float4 a = *(const float4*)(p + (size_t)(2 * t) * 1024 + c);
    float4 b = *(const float4*)(p + (size_t)(2 * t + 1) * 1024 + c);
    s0.x += a.x; s0.y += a.y; s0.z += a.z; s0.w += a.w;
    s1.x += b.x; s1.y += b.y; s1.z += b.z; s1.w += b.w;
  }
  float4 o = *(float4*)(outp + i4);
  o.x += w0 * s0.x + w1 * s1.x;
  o.y += w0 * s0.y + w1 * s1.y;
  o.z += w0 * s0.z + w1 * s1.z;
  o.w += w0 * s0.w + w1 * s1.w;
  *(float4*)(outp + i4) = o;
}

extern "C" void kernel_launch(void* const* d_in, const int* in_sizes, int n_in,
                              void* d_out, int out_size, void* d_ws, size_t ws_size,
                              hipStream_t stream) {
  const int* positions = (const int*)d_in[0];
  const float* hidden = (const float*)d_in[1];
  const float* in_ln = (const float*)d_in[2];
  const float* post_ln = (const float*)d_in[3];
  const float* res_ln = (const float*)d_in[4];
  const float* qkv_w = (const float*)d_in[5];
  const float* o_w = (const float*)d_in[6];
  const float* gate_w = (const float*)d_in[7];
  const float* ws_w = (const float*)d_in[8];
  const float* w2s_w = (const float*)d_in[9];
  const float* w13_w = (const float*)d_in[10];
  const float* w2_w = (const float*)d_in[11];
  float* out = (float*)d_out;

  char* p = (char*)d_ws;
  auto alloc = [&](size_t b) { void* r = (void*)p; p += (b + 255) & ~(size_t)255; return r; };

  f16* wqkv = (f16*)alloc((size_t)1536 * 1024 * 2);
  f16* woh  = (f16*)alloc((size_t)1024 * 1024 * 2);
  f16* wol  = (f16*)alloc((size_t)1024 * 1024 * 2);
  f16* wws  = (f16*)alloc((size_t)8 * 4096 * 1024 * 2);
  f16* ww2  = (f16*)alloc((size_t)8 * 1024 * 2048 * 2);
  f16* w13  = (f16*)alloc((size_t)2048 * 1024 * 2);
  f16* w2c  = (f16*)alloc((size_t)1024 * 1024 * 2);
  f16* hn   = (f16*)alloc((size_t)2048 * 1024 * 2);
  float* qkvp = (float*)alloc((size_t)2 * 2048 * 1536 * 4);  // qkv split partials
  float2* ptab = (float2*)alloc((size_t)2048 * 32 * 8);      // rope phase table
  f16* qr = (f16*)alloc((size_t)2048 * 1024 * 2);
  f16* kr = (f16*)alloc((size_t)2048 * 256 * 2);
  f16* vt = (f16*)alloc((size_t)256 * 2048 * 2);
  f16* ath = (f16*)alloc((size_t)2048 * 1024 * 2);
  f16* atl = (f16*)alloc((size_t)2048 * 1024 * 2);
  float* opp = (float*)alloc((size_t)2 * 2048 * 1024 * 4);   // o-proj split partials
  float* resA = (float*)alloc((size_t)2048 * 1024 * 4);
  f16* rn = (f16*)alloc((size_t)2048 * 1024 * 2);
  f16* mn = (f16*)alloc((size_t)2048 * 1024 * 2);
  f16* gu13 = (f16*)alloc((size_t)2048 * 2048 * 2);
  f16* act13 = (f16*)alloc((size_t)2048 * 1024 * 2);
  float* w2p = (float*)alloc((size_t)2 * 2048 * 1024 * 4);   // w2 split partials
  f16* actm = (f16*)alloc((size_t)4096 * 2048 * 2);
  float* eo2 = (float*)alloc((size_t)2 * 4096 * 1024 * 4);   // down-proj split partials
  float* rw = (float*)alloc((size_t)4096 * 4);
  int* counts = (int*)alloc(256);
  int* perm = (int*)alloc((size_t)8 * 2048 * 4);

  // weight conversions (ws is re-poisoned before every timed launch)
  cvt_f16_kernel<<<dim3(1536 * 1024 / 1024), dim3(256), 0, stream>>>(qkv_w, wqkv);
  cvt_f16_kernel<<<dim3(8 * 4096 * 1024 / 1024), dim3(256), 0, stream>>>(ws_w, wws);
  cvt_f16_kernel<<<dim3(8 * 1024 * 2048 / 1024), dim3(256), 0, stream>>>(w2s_w, ww2);
  cvt_f16_kernel<<<dim3(2048 * 1024 / 1024), dim3(256), 0, stream>>>(w13_w, w13);
  cvt_f16_kernel<<<dim3(1024 * 1024 / 1024), dim3(256), 0, stream>>>(w2_w, w2c);
  cvt_f16x2_kernel<<<dim3(1024 * 1024 / 1024), dim3(256), 0, stream>>>(o_w, woh, wol);
  rope_table_kernel<<<dim3(256), dim3(256), 0, stream>>>(positions, ptab);
  hipMemsetAsync(counts, 0, 256, stream);

  // attention path
  rmsnorm_kernel<<<dim3(512), dim3(256), 0, stream>>>(hidden, in_ln, hn);
  gemm_f16_kernel<0, 64, 2><<<dim3(24, 16, 2), dim3(256), 0, stream>>>(
      hn, wqkv, (void*)qkvp, (const float*)nullptr, 2048, 1536, 1024);
  rope_kernel<<<dim3(3, 2048), dim3(256), 0, stream>>>(qkvp, ptab, qr, kr);
  vtrans_kernel<<<dim3(32, 4), dim3(256), 0, stream>>>(qkvp, vt);
  attn_kernel<<<dim3(32, 16), dim3(256), 0, stream>>>(qr, kr, vt, ath, atl);
  gemm_f16x2_add_kernel<2><<<dim3(16, 16, 2), dim3(256), 0, stream>>>(
      ath, atl, woh, wol, opp, (const float*)nullptr, 2048, 1024, 1024);
  add3_kernel<<<dim3(2048), dim3(256), 0, stream>>>(
      resA, hidden, opp, opp + (size_t)2048 * 1024);

  // norms + routing off residual_attn
  rmsnorm_dual_kernel<<<dim3(512), dim3(256), 0, stream>>>(resA, res_ln, post_ln, rn, mn);
  routing_kernel<<<dim3(512), dim3(256), 0, stream>>>(resA, post_ln, gate_w, counts, perm, rw);

  // residual MLP -> d_out holds residual_mlp
  gemm_f16_kernel<2, 64><<<dim3(32, 16), dim3(256), 0, stream>>>(
      rn, w13, (void*)gu13, (const float*)nullptr, 2048, 2048, 1024);
  silu_mul_kernel<<<dim3(2048 * 1024 / 1024), dim3(256), 0, stream>>>(gu13, act13, 10);
  gemm_f16_kernel<0, 64, 2><<<dim3(16, 16, 2), dim3(256), 0, stream>>>(
      act13, w2c, (void*)w2p, (const float*)nullptr, 2048, 1024, 1024);
  add3_kernel<<<dim3(2048), dim3(256), 0, stream>>>(
      out, resA, w2p, w2p + (size_t)2048 * 1024);

  // MoE (top-2 sparse): gated up-proj writes silu(g)*u directly to actm
  gemm_moe_gated_kernel<<<dim3(32, 16, 8), dim3(256), 0, stream>>>(
      mn, wws, actm, perm, counts, 1024, (size_t)4096 * 1024);
  gemm_moe_kernel<0, 128, 2><<<dim3(8, 16, 16), dim3(256), 0, stream>>>(
      actm, ww2, (void*)eo2, perm, counts, 1024, 2048, (size_t)1024 * 2048);
  final_add2_kernel<<<dim3(2048 * 1024 / 1024), dim3(256), 0, stream>>>(out, eo2, rw);
}